// Round 11
// baseline (3121.418 us; speedup 1.0000x reference)
//
#include <hip/hip_runtime.h>
#include <type_traits>

#define EMB_D 64
#define NCLS 8      // row-range partitions for degree kernel (XCD heuristic)
#define CSHIFT 7    // class = row >> 7 (128 rows/class)
#define CROWS  (1 << CSHIFT)
#define CMASK  (CROWS - 1)
#define MAXC 1280   // max classes (M <= 163840; col fits 18 bits)
#define CPAD 16     // bkcur padding: one counter per 64B line

typedef float    float4v __attribute__((ext_vector_type(4)));
typedef _Float16 half4v  __attribute__((ext_vector_type(4)));

__device__ inline float4v tof32(half4v v)  { return __builtin_convertvector(v, float4v); }
__device__ inline float4v tof32(float4v v) { return v; }

// ---------------------------------------------------------------------------
// fused partitioned degree kernel: bip degrees (deg, both dirs) + s-row
// degrees (degs). Class c only touches dst rows in its 1/8 of [0,M).
// ---------------------------------------------------------------------------
__global__ void deg_part_kernel(const int* __restrict__ eu, const int* __restrict__ ei,
                                int E, int U,
                                const int* __restrict__ sr, int S, int M,
                                int* __restrict__ deg, int* __restrict__ degs) {
    int cls = blockIdx.x & (NCLS - 1);
    long e  = ((long)(blockIdx.x >> 3)) * blockDim.x + threadIdx.x;
    int lo = (int)((long)cls * M / NCLS), hi = (int)((long)(cls + 1) * M / NCLS);
    if (e < E) {
        int u  = eu[e];
        int iv = U + ei[e];
        if (u  >= lo && u  < hi) atomicAdd(&deg[u], 1);
        if (iv >= lo && iv < hi) atomicAdd(&deg[iv], 1);
    }
    if (e < S) {
        int r = sr[e];
        int dst = U + r;
        if (dst >= lo && dst < hi) atomicAdd(&degs[r], 1);
    }
}

// ---------------------------------------------------------------------------
// per-class entry totals (bip + s) and norm = rsqrt(deg+1), one block/class
// ---------------------------------------------------------------------------
__global__ void __launch_bounds__(CROWS) class_tot(const int* __restrict__ deg,
                                                   const int* __restrict__ degs,
                                                   int U, int M,
                                                   float* __restrict__ norm,
                                                   int* __restrict__ ctot) {
    __shared__ int sh[CROWS];
    int row = (blockIdx.x << CSHIFT) + threadIdx.x;
    int len = 0;
    if (row < M) {
        int d = deg[row];
        norm[row] = rsqrtf((float)d + 1.0f);
        len = d + (row >= U ? degs[row - U] : 0);
    }
    sh[threadIdx.x] = len;
    __syncthreads();
    for (int ofs = CROWS / 2; ofs > 0; ofs >>= 1) {
        if (threadIdx.x < ofs) sh[threadIdx.x] += sh[threadIdx.x + ofs];
        __syncthreads();
    }
    if (threadIdx.x == 0) ctot[blockIdx.x] = sh[0];
}

// ---------------------------------------------------------------------------
// single-block exclusive scan over NC (<=2048) class totals -> bkptr, bkcur
// (each thread owns classes 2t, 2t+1)
// ---------------------------------------------------------------------------
__global__ void __launch_bounds__(1024) class_scan(const int* __restrict__ ctot, int NC,
                                                   int* __restrict__ bkptr,
                                                   int* __restrict__ bkcur) {
    __shared__ int sh[1024];
    int t = threadIdx.x;
    int v0 = (2 * t     < NC) ? ctot[2 * t]     : 0;
    int v1 = (2 * t + 1 < NC) ? ctot[2 * t + 1] : 0;
    int s = v0 + v1;
    sh[t] = s;
    __syncthreads();
    for (int ofs = 1; ofs < 1024; ofs <<= 1) {
        int x = (t >= ofs) ? sh[t - ofs] : 0;
        __syncthreads();
        sh[t] += x;
        __syncthreads();
    }
    int excl = sh[t] - s;
    if (2 * t < NC)     { bkptr[2 * t]     = excl;      bkcur[(2 * t) * CPAD]     = excl; }
    if (2 * t + 1 < NC) { bkptr[2 * t + 1] = excl + v0; bkcur[(2 * t + 1) * CPAD] = excl + v0; }
    if (t == 1023) bkptr[NC] = sh[1023];
}

// ---------------------------------------------------------------------------
// bin entries into per-class buckets. 512 edges per block (2/thread).
// LDS histogram -> ONE padded global atomicAdd per (block, class) ->
// contiguous per-block chunks (dense writes).
// Bucket entry: (row_lo<<18 | col, w_bits).
// ---------------------------------------------------------------------------
__global__ void __launch_bounds__(256) bin_kernel(const int* __restrict__ eu,
                                                  const int* __restrict__ ei,
                                                  int E, int nbE,
                                                  const int* __restrict__ sr,
                                                  const int* __restrict__ sc,
                                                  const float* __restrict__ sv, int S,
                                                  int U, const float* __restrict__ norm,
                                                  int* __restrict__ bkcur,
                                                  int2* __restrict__ bent) {
    __shared__ int hist[MAXC];
    __shared__ int base[MAXC];
    for (int t = threadIdx.x; t < MAXC; t += 256) hist[t] = 0;
    __syncthreads();

    int blk = blockIdx.x;
    int c0 = -1, c1 = -1, c2 = -1, c3 = -1;
    int2 v0, v1, v2, v3;
    if (blk < nbE) {
        {
            int e = blk * 512 + threadIdx.x;
            if (e < E) {
                int u  = eu[e];
                int iv = U + ei[e];
                int wb = __float_as_int(norm[u] * norm[iv]);
                c0 = u >> CSHIFT;  v0 = make_int2(((u & CMASK) << 18) | iv, wb);
                c1 = iv >> CSHIFT; v1 = make_int2(((iv & CMASK) << 18) | u, wb);
                atomicAdd(&hist[c0], 1);
                atomicAdd(&hist[c1], 1);
            }
        }
        {
            int e = blk * 512 + 256 + threadIdx.x;
            if (e < E) {
                int u  = eu[e];
                int iv = U + ei[e];
                int wb = __float_as_int(norm[u] * norm[iv]);
                c2 = u >> CSHIFT;  v2 = make_int2(((u & CMASK) << 18) | iv, wb);
                c3 = iv >> CSHIFT; v3 = make_int2(((iv & CMASK) << 18) | u, wb);
                atomicAdd(&hist[c2], 1);
                atomicAdd(&hist[c3], 1);
            }
        }
    } else {
        {
            int e = (blk - nbE) * 512 + threadIdx.x;
            if (e < S) {
                int dst = U + sr[e];
                c0 = dst >> CSHIFT;
                v0 = make_int2(((dst & CMASK) << 18) | (U + sc[e]), __float_as_int(sv[e]));
                atomicAdd(&hist[c0], 1);
            }
        }
        {
            int e = (blk - nbE) * 512 + 256 + threadIdx.x;
            if (e < S) {
                int dst = U + sr[e];
                c1 = dst >> CSHIFT;
                v1 = make_int2(((dst & CMASK) << 18) | (U + sc[e]), __float_as_int(sv[e]));
                atomicAdd(&hist[c1], 1);
            }
        }
    }
    __syncthreads();
    for (int t = threadIdx.x; t < MAXC; t += 256) {
        int h = hist[t];
        base[t] = h ? atomicAdd(&bkcur[t * CPAD], h) : 0;
        hist[t] = 0;
    }
    __syncthreads();
    if (c0 >= 0) { int o = atomicAdd(&hist[c0], 1); bent[base[c0] + o] = v0; }
    if (c1 >= 0) { int o = atomicAdd(&hist[c1], 1); bent[base[c1] + o] = v1; }
    if (c2 >= 0) { int o = atomicAdd(&hist[c2], 1); bent[base[c2] + o] = v2; }
    if (c3 >= 0) { int o = atomicAdd(&hist[c3], 1); bent[base[c3] + o] = v3; }
}

// ---------------------------------------------------------------------------
// cur0 (fp16) = concat(user_emb, item_emb)
// ---------------------------------------------------------------------------
__global__ void init_kernel(const float4v* __restrict__ ue, const float4v* __restrict__ ie,
                            long u4, long total4, half4v* __restrict__ curH) {
    long stride = (long)gridDim.x * blockDim.x;
    for (long idx = (long)blockIdx.x * blockDim.x + threadIdx.x; idx < total4; idx += stride) {
        float4v v = (idx < u4) ? ue[idx] : ie[idx - u4];
        curH[idx] = __builtin_convertvector(v, half4v);
    }
}

// ---------------------------------------------------------------------------
// fused gather: one block per 128-row class, 32 KB LDS fp32 accumulator.
// Streams the class's (unordered) bucket entries with 16-lane quarter-waves,
// 4-deep pipelined row loads; accumulates via row-swizzled LDS atomicAdd.
// MODE 0: read fp16 curH -> write fp16 dstH          (e0 -> e1)
// MODE 1: read fp16 curH -> dstF=e2 (fp32), out = e0+e1+e2
// MODE 2: read fp32 curF -> out = 0.25*(out + e3)
// ---------------------------------------------------------------------------
template <int MODE>
__global__ void __launch_bounds__(256) gather_fused(const int* __restrict__ bkptr,
                                                    const int2* __restrict__ bent,
                                                    const _Float16* __restrict__ curH,
                                                    const float* __restrict__ curF,
                                                    const _Float16* __restrict__ cur0H,
                                                    _Float16* __restrict__ dstH,
                                                    float* __restrict__ dstF,
                                                    float* __restrict__ out, int M) {
    using VecT = typename std::conditional<MODE == 2, float4v, half4v>::type;
    __shared__ float acc[CROWS * EMB_D];           // 32 KB
    int c   = blockIdx.x;
    int rlo = c << CSHIFT;
    int nrows = min(CROWS, M - rlo);

    for (int i = threadIdx.x; i < CROWS * 16; i += 256) {
        float4v z = {0.f, 0.f, 0.f, 0.f};
        ((float4v*)acc)[i] = z;
    }
    __syncthreads();

    int beg = bkptr[c], end = bkptr[c + 1];
    int qw = threadIdx.x >> 4;     // 0..15
    int l  = threadIdx.x & 15;
    const VecT* curv = (MODE == 2) ? (const VecT*)(const void*)curF
                                   : (const VecT*)(const void*)curH;

    auto flush = [&](int2 a, VecT v) {
        float4v f = __int_as_float(a.y) * tof32(v);
        int row_lo = ((unsigned)a.x) >> 18;
        int swl = (l + row_lo) & 15;               // bank swizzle by row
        float* d = &acc[row_lo * EMB_D + swl * 4];
        atomicAdd(d + 0, f.x);
        atomicAdd(d + 1, f.y);
        atomicAdd(d + 2, f.z);
        atomicAdd(d + 3, f.w);
    };

    int k = beg + qw;
    int2 a0 = (k      < end) ? bent[k]      : make_int2(0, 0);
    int2 a1 = (k + 16 < end) ? bent[k + 16] : make_int2(0, 0);
    int2 a2 = (k + 32 < end) ? bent[k + 32] : make_int2(0, 0);
    int2 a3 = (k + 48 < end) ? bent[k + 48] : make_int2(0, 0);
    VecT v0 = curv[(long)(a0.x & 0x3FFFF) * 16 + l];
    VecT v1 = curv[(long)(a1.x & 0x3FFFF) * 16 + l];
    VecT v2 = curv[(long)(a2.x & 0x3FFFF) * 16 + l];
    VecT v3 = curv[(long)(a3.x & 0x3FFFF) * 16 + l];
    while (k + 64 < end) {
        int kn = k + 64;
        int2 b0 = (kn      < end) ? bent[kn]      : make_int2(0, 0);
        int2 b1 = (kn + 16 < end) ? bent[kn + 16] : make_int2(0, 0);
        int2 b2 = (kn + 32 < end) ? bent[kn + 32] : make_int2(0, 0);
        int2 b3 = (kn + 48 < end) ? bent[kn + 48] : make_int2(0, 0);
        VecT u0 = curv[(long)(b0.x & 0x3FFFF) * 16 + l];
        VecT u1 = curv[(long)(b1.x & 0x3FFFF) * 16 + l];
        VecT u2 = curv[(long)(b2.x & 0x3FFFF) * 16 + l];
        VecT u3 = curv[(long)(b3.x & 0x3FFFF) * 16 + l];
        flush(a0, v0); flush(a1, v1); flush(a2, v2); flush(a3, v3);
        a0 = b0; a1 = b1; a2 = b2; a3 = b3;
        v0 = u0; v1 = u1; v2 = u2; v3 = u3;
        k = kn;
    }
    flush(a0, v0); flush(a1, v1); flush(a2, v2); flush(a3, v3);

    __syncthreads();

    for (int i = threadIdx.x; i < nrows * 16; i += 256) {
        int row_lo = i >> 4;
        int ll = i & 15;
        int swl = (ll + row_lo) & 15;
        float4v a = ((float4v*)acc)[row_lo * 16 + swl];
        long o4 = (long)(rlo + row_lo) * 16 + ll;
        if (MODE == 0) {
            ((half4v*)dstH)[o4] = __builtin_convertvector(a, half4v);
        } else if (MODE == 1) {
            float4v e0 = tof32(((const half4v*)cur0H)[o4]);
            float4v e1 = tof32(((const half4v*)curH)[o4]);
            ((float4v*)dstF)[o4] = a;
            ((float4v*)out)[o4]  = e0 + e1 + a;
        } else {
            float4v pv = ((const float4v*)out)[o4];
            ((float4v*)out)[o4] = 0.25f * (pv + a);
        }
    }
}

extern "C" void kernel_launch(void* const* d_in, const int* in_sizes, int n_in,
                              void* d_out, int out_size, void* d_ws, size_t ws_size,
                              hipStream_t stream) {
    const float* user_emb = (const float*)d_in[0];
    const float* item_emb = (const float*)d_in[1];
    const int*   edge_user = (const int*)d_in[2];
    const int*   edge_item = (const int*)d_in[3];
    const int*   s_row = (const int*)d_in[4];
    const int*   s_col = (const int*)d_in[5];
    const float* s_val = (const float*)d_in[6];
    float* out = (float*)d_out;

    const int U = in_sizes[0] / EMB_D;
    const int I = in_sizes[1] / EMB_D;
    const int M = U + I;
    const int E = in_sizes[2];
    const int S = in_sizes[4];
    const long MD = (long)M * EMB_D;
    const long NT = 2L * E + S;             // total bucket entries
    const int NC = (M + CMASK) >> CSHIFT;   // number of row classes

    // workspace carve-up, 16B-aligned chunks
    char* p = (char*)d_ws;
    auto carve = [&](long bytes) {
        char* q = p;
        p += (bytes + 15) & ~15L;
        return q;
    };
    _Float16* cur0H = (_Float16*)carve(MD * sizeof(_Float16));  // e0 (fp16)
    _Float16* cur1H = (_Float16*)carve(MD * sizeof(_Float16));  // e1 (fp16)
    float*    bufC  = (float*)carve(MD * sizeof(float));        // e2 (fp32)
    int2*     bent  = (int2*)carve((NT + 64) * sizeof(int2));   // class buckets
    float*  norm    = (float*)carve((long)M * sizeof(float));
    int*    deg_all = (int*)carve((long)(M + I) * sizeof(int)); // deg | degs adjacent
    int*    deg     = deg_all;
    int*    degs    = deg_all + M;
    int*    ctot    = (int*)carve((long)MAXC * sizeof(int));
    int*    bkptr   = (int*)carve((long)(MAXC + 1) * sizeof(int));
    int*    bkcur   = (int*)carve((long)MAXC * CPAD * sizeof(int));

    const int nbE = (E + 255) / 256;
    const int nbS = (S + 255) / 256;
    const int nbMax = (nbE > nbS) ? nbE : nbS;
    const int nbE2 = (E + 511) / 512;       // bin blocks (512 edges each)
    const int nbS2 = (S + 511) / 512;

    // 1) fused partitioned degrees
    hipMemsetAsync(deg_all, 0, (size_t)(M + I) * sizeof(int), stream);
    deg_part_kernel<<<NCLS * nbMax, 256, 0, stream>>>(edge_user, edge_item, E, U,
                                                      s_row, S, M, deg, degs);

    // 2) per-class totals (+norm), tiny scan -> bkptr / padded bkcur
    class_tot<<<NC, CROWS, 0, stream>>>(deg, degs, U, M, norm, ctot);
    class_scan<<<1, 1024, 0, stream>>>(ctot, NC, bkptr, bkcur);

    // 3) bin entries into class buckets (dense appends)
    bin_kernel<<<nbE2 + nbS2, 256, 0, stream>>>(edge_user, edge_item, E, nbE2,
                                                s_row, s_col, s_val, S,
                                                U, norm, bkcur, bent);

    // 4) init cur0 (fp16)
    init_kernel<<<2048, 256, 0, stream>>>((const float4v*)user_emb, (const float4v*)item_emb,
                                          (long)U * (EMB_D / 4), MD / 4, (half4v*)cur0H);

    // 5) L=3 fused gather layers (LDS class accumulators, no CSR)
    gather_fused<0><<<NC, 256, 0, stream>>>(bkptr, bent, cur0H, nullptr, nullptr,
                                            cur1H, nullptr, nullptr, M);
    gather_fused<1><<<NC, 256, 0, stream>>>(bkptr, bent, cur1H, nullptr, cur0H,
                                            nullptr, bufC, out, M);
    gather_fused<2><<<NC, 256, 0, stream>>>(bkptr, bent, nullptr, bufC, nullptr,
                                            nullptr, nullptr, out, M);
}

// Round 12
// 429.270 us; speedup vs baseline: 7.2715x; 7.2715x over previous
//
#include <hip/hip_runtime.h>
#include <type_traits>

#define EMB_D 64
#define NCLS 8      // row-range partitions for degree kernel (XCD heuristic)
#define CSHIFT 9    // class = row >> 9 (512 rows/class)
#define CROWS  (1 << CSHIFT)
#define CMASK  (CROWS - 1)
#define MAXC 384    // max classes (M <= 196608; col fits 18 bits)
#define CPAD 16     // bkcur padding: one counter per 64B line

typedef float    float4v __attribute__((ext_vector_type(4)));
typedef _Float16 half4v  __attribute__((ext_vector_type(4)));

__device__ inline float4v tof32(half4v v)  { return __builtin_convertvector(v, float4v); }
__device__ inline float4v tof32(float4v v) { return v; }

// ---------------------------------------------------------------------------
// fused partitioned degree kernel: bip degrees (deg, both dirs) + s-row
// degrees (degs). Class c only touches dst rows in its 1/8 of [0,M).
// ---------------------------------------------------------------------------
__global__ void deg_part_kernel(const int* __restrict__ eu, const int* __restrict__ ei,
                                int E, int U,
                                const int* __restrict__ sr, int S, int M,
                                int* __restrict__ deg, int* __restrict__ degs) {
    int cls = blockIdx.x & (NCLS - 1);
    long e  = ((long)(blockIdx.x >> 3)) * blockDim.x + threadIdx.x;
    int lo = (int)((long)cls * M / NCLS), hi = (int)((long)(cls + 1) * M / NCLS);
    if (e < E) {
        int u  = eu[e];
        int iv = U + ei[e];
        if (u  >= lo && u  < hi) atomicAdd(&deg[u], 1);
        if (iv >= lo && iv < hi) atomicAdd(&deg[iv], 1);
    }
    if (e < S) {
        int r = sr[e];
        int dst = U + r;
        if (dst >= lo && dst < hi) atomicAdd(&degs[r], 1);
    }
}

// ---------------------------------------------------------------------------
// scan phase 1 over combined row lengths; also emits norm = rsqrt(deg+1).
// ---------------------------------------------------------------------------
__global__ void __launch_bounds__(1024) scan_block(const int* __restrict__ deg,
                                                   const int* __restrict__ degs,
                                                   int U, int n,
                                                   float* __restrict__ norm,
                                                   int* __restrict__ incl,
                                                   int* __restrict__ bsum) {
    __shared__ int sh[1024];
    int i = blockIdx.x * 1024 + threadIdx.x;
    int d = (i < n) ? deg[i] : 0;
    int v = d;
    if (i < n && i >= U) v += degs[i - U];
    if (i < n) norm[i] = rsqrtf((float)d + 1.0f);
    sh[threadIdx.x] = v;
    __syncthreads();
    for (int ofs = 1; ofs < 1024; ofs <<= 1) {
        int t = (threadIdx.x >= ofs) ? sh[threadIdx.x - ofs] : 0;
        __syncthreads();
        sh[threadIdx.x] += t;
        __syncthreads();
    }
    if (i < n) incl[i] = sh[threadIdx.x];
    if (threadIdx.x == 1023) bsum[blockIdx.x] = sh[1023];
}

__global__ void __launch_bounds__(256) scan_bsum(int* __restrict__ bsum, int nb) {
    __shared__ int sh[256];
    int v = (threadIdx.x < nb) ? bsum[threadIdx.x] : 0;
    sh[threadIdx.x] = v;
    __syncthreads();
    for (int ofs = 1; ofs < 256; ofs <<= 1) {
        int t = (threadIdx.x >= ofs) ? sh[threadIdx.x - ofs] : 0;
        __syncthreads();
        sh[threadIdx.x] += t;
        __syncthreads();
    }
    if (threadIdx.x < nb) bsum[threadIdx.x] = sh[threadIdx.x] - v;  // exclusive
}

// rowptr + per-class bucket cursors (padded) + class table
__global__ void finalize_rowptr(const int* __restrict__ incl, const int* __restrict__ deg,
                                const int* __restrict__ degs,
                                const int* __restrict__ bsum, int U, int n, int NC,
                                int* __restrict__ rowptr,
                                int* __restrict__ bkcur, int* __restrict__ bkptr) {
    int i = blockIdx.x * blockDim.x + threadIdx.x;
    if (i < n) {
        int len = deg[i] + (i >= U ? degs[i - U] : 0);
        int v = incl[i] - len + bsum[i >> 10];
        rowptr[i] = v;
        if ((i & CMASK) == 0) {
            bkcur[(i >> CSHIFT) * CPAD] = v;   // one counter per 64B line
            bkptr[i >> CSHIFT] = v;
        }
    } else if (i == n) {
        int tot = incl[n - 1] + bsum[(n - 1) >> 10];
        rowptr[n] = tot;
        bkptr[NC] = tot;
    }
}

// ---------------------------------------------------------------------------
// pass 1: bin entries into per-class buckets. 512 edges per block (2/thread,
// statically unrolled). LDS histogram -> ONE padded global atomicAdd per
// (block, class) -> contiguous per-block chunks (dense writes).
// Bucket entry: (row_lo<<18 | col, w_bits).
// ---------------------------------------------------------------------------
__global__ void __launch_bounds__(256) bin_kernel(const int* __restrict__ eu,
                                                  const int* __restrict__ ei,
                                                  int E, int nbE,
                                                  const int* __restrict__ sr,
                                                  const int* __restrict__ sc,
                                                  const float* __restrict__ sv, int S,
                                                  int U, const float* __restrict__ norm,
                                                  int* __restrict__ bkcur,
                                                  int2* __restrict__ bent) {
    __shared__ int hist[MAXC];
    __shared__ int base[MAXC];
    for (int t = threadIdx.x; t < MAXC; t += 256) hist[t] = 0;
    __syncthreads();

    int blk = blockIdx.x;
    int c0 = -1, c1 = -1, c2 = -1, c3 = -1;
    int2 v0, v1, v2, v3;
    if (blk < nbE) {
        {
            int e = blk * 512 + threadIdx.x;
            if (e < E) {
                int u  = eu[e];
                int iv = U + ei[e];
                int wb = __float_as_int(norm[u] * norm[iv]);
                c0 = u >> CSHIFT;  v0 = make_int2(((u & CMASK) << 18) | iv, wb);
                c1 = iv >> CSHIFT; v1 = make_int2(((iv & CMASK) << 18) | u, wb);
                atomicAdd(&hist[c0], 1);
                atomicAdd(&hist[c1], 1);
            }
        }
        {
            int e = blk * 512 + 256 + threadIdx.x;
            if (e < E) {
                int u  = eu[e];
                int iv = U + ei[e];
                int wb = __float_as_int(norm[u] * norm[iv]);
                c2 = u >> CSHIFT;  v2 = make_int2(((u & CMASK) << 18) | iv, wb);
                c3 = iv >> CSHIFT; v3 = make_int2(((iv & CMASK) << 18) | u, wb);
                atomicAdd(&hist[c2], 1);
                atomicAdd(&hist[c3], 1);
            }
        }
    } else {
        {
            int e = (blk - nbE) * 512 + threadIdx.x;
            if (e < S) {
                int dst = U + sr[e];
                c0 = dst >> CSHIFT;
                v0 = make_int2(((dst & CMASK) << 18) | (U + sc[e]), __float_as_int(sv[e]));
                atomicAdd(&hist[c0], 1);
            }
        }
        {
            int e = (blk - nbE) * 512 + 256 + threadIdx.x;
            if (e < S) {
                int dst = U + sr[e];
                c1 = dst >> CSHIFT;
                v1 = make_int2(((dst & CMASK) << 18) | (U + sc[e]), __float_as_int(sv[e]));
                atomicAdd(&hist[c1], 1);
            }
        }
    }
    __syncthreads();
    for (int t = threadIdx.x; t < MAXC; t += 256) {
        int h = hist[t];
        base[t] = h ? atomicAdd(&bkcur[t * CPAD], h) : 0;
        hist[t] = 0;
    }
    __syncthreads();
    if (c0 >= 0) { int o = atomicAdd(&hist[c0], 1); bent[base[c0] + o] = v0; }
    if (c1 >= 0) { int o = atomicAdd(&hist[c1], 1); bent[base[c1] + o] = v1; }
    if (c2 >= 0) { int o = atomicAdd(&hist[c2], 1); bent[base[c2] + o] = v2; }
    if (c3 >= 0) { int o = atomicAdd(&hist[c3], 1); bent[base[c3] + o] = v3; }
}

// ---------------------------------------------------------------------------
// pass 2: one 1024-thread block per 512-row class. Row cursors in LDS (2 KB,
// no global atomics). Reads its ~68 KB bucket slice sequentially and
// scatters into its exclusively-owned ~68 KB CSR window: single XCD,
// temporally dense -> lines fill in L2 before writeback (~1x write amp).
// 293 blocks saturate the CUs (round-8's defect was 74 blocks).
// ---------------------------------------------------------------------------
__global__ void __launch_bounds__(1024) csr_scatter(const int* __restrict__ rowptr,
                                                    const int* __restrict__ bkptr,
                                                    const int2* __restrict__ bent,
                                                    int2* __restrict__ ent, int M) {
    __shared__ int cur[CROWS];
    int c   = blockIdx.x;
    int rlo = c << CSHIFT;
    int nrows = min(CROWS, M - rlo);
    for (int r = threadIdx.x; r < nrows; r += 1024)
        cur[r] = rowptr[rlo + r];
    __syncthreads();
    int beg = bkptr[c], end = bkptr[c + 1];
    for (int k = beg + threadIdx.x; k < end; k += 1024) {
        int2 e = bent[k];
        int rl  = ((unsigned)e.x) >> 18;
        int col = e.x & 0x3FFFF;
        int p = atomicAdd(&cur[rl], 1);
        ent[p] = make_int2(col, e.y);
    }
}

// ---------------------------------------------------------------------------
// cur0 (fp16) = concat(user_emb, item_emb)
// ---------------------------------------------------------------------------
__global__ void init_kernel(const float4v* __restrict__ ue, const float4v* __restrict__ ie,
                            long u4, long total4, half4v* __restrict__ curH) {
    long stride = (long)gridDim.x * blockDim.x;
    for (long idx = (long)blockIdx.x * blockDim.x + threadIdx.x; idx < total4; idx += stride) {
        float4v v = (idx < u4) ? ue[idx] : ie[idx - u4];
        curH[idx] = __builtin_convertvector(v, half4v);
    }
}

// ---------------------------------------------------------------------------
// gather: ONE 16-lane quarter-wave per destination row (4 rows per wave),
// 4-deep masked software pipeline -> 16 outstanding row loads per wave.
// Heavy-first: item rows dispatched first, users fill the tail.
// MODE 0: read fp16 curH -> write fp16 dstH          (e0 -> e1)
// MODE 1: read fp16 curH -> dstF=e2 (fp32), out = e0+e1+e2
// MODE 2: read fp32 curF -> out = 0.25*(out + e3)
// ---------------------------------------------------------------------------
template <int MODE>
__global__ void __launch_bounds__(256) gather_kernel(const int* __restrict__ rowptr,
                                                     const int2* __restrict__ ent,
                                                     const _Float16* __restrict__ curH,
                                                     const float* __restrict__ curF,
                                                     const _Float16* __restrict__ cur0H,
                                                     _Float16* __restrict__ dstH,
                                                     float* __restrict__ dstF,
                                                     float* __restrict__ out,
                                                     int U, int I, int M) {
    using VecT = typename std::conditional<MODE == 2, float4v, half4v>::type;
    int raw = (int)((((long)blockIdx.x * blockDim.x) + threadIdx.x) >> 4);
    int l   = threadIdx.x & 15;
    if (raw >= M) return;
    int row = (raw < I) ? (U + raw) : (raw - I);
    int beg = rowptr[row];
    int end = rowptr[row + 1];
    const VecT* curv = (MODE == 2) ? (const VecT*)(const void*)curF
                                   : (const VecT*)(const void*)curH;

    float4v acc = {0.f, 0.f, 0.f, 0.f};
    int j = beg;
    int2 a0 = (j + 0 < end) ? ent[j + 0] : make_int2(0, 0);
    int2 a1 = (j + 1 < end) ? ent[j + 1] : make_int2(0, 0);
    int2 a2 = (j + 2 < end) ? ent[j + 2] : make_int2(0, 0);
    int2 a3 = (j + 3 < end) ? ent[j + 3] : make_int2(0, 0);
    VecT v0 = curv[(long)a0.x * 16 + l];
    VecT v1 = curv[(long)a1.x * 16 + l];
    VecT v2 = curv[(long)a2.x * 16 + l];
    VecT v3 = curv[(long)a3.x * 16 + l];
    while (j + 4 < end) {
        int jn = j + 4;
        int2 b0 = (jn + 0 < end) ? ent[jn + 0] : make_int2(0, 0);
        int2 b1 = (jn + 1 < end) ? ent[jn + 1] : make_int2(0, 0);
        int2 b2 = (jn + 2 < end) ? ent[jn + 2] : make_int2(0, 0);
        int2 b3 = (jn + 3 < end) ? ent[jn + 3] : make_int2(0, 0);
        VecT u0 = curv[(long)b0.x * 16 + l];
        VecT u1 = curv[(long)b1.x * 16 + l];
        VecT u2 = curv[(long)b2.x * 16 + l];
        VecT u3 = curv[(long)b3.x * 16 + l];
        acc += __int_as_float(a0.y) * tof32(v0);
        acc += __int_as_float(a1.y) * tof32(v1);
        acc += __int_as_float(a2.y) * tof32(v2);
        acc += __int_as_float(a3.y) * tof32(v3);
        a0 = b0; a1 = b1; a2 = b2; a3 = b3;
        v0 = u0; v1 = u1; v2 = u2; v3 = u3;
        j = jn;
    }
    acc += __int_as_float(a0.y) * tof32(v0);
    acc += __int_as_float(a1.y) * tof32(v1);
    acc += __int_as_float(a2.y) * tof32(v2);
    acc += __int_as_float(a3.y) * tof32(v3);

    long o4 = (long)row * 16 + l;
    if (MODE == 0) {
        ((half4v*)dstH)[o4] = __builtin_convertvector(acc, half4v);
    } else if (MODE == 1) {
        float4v e0 = tof32(((const half4v*)cur0H)[o4]);
        float4v e1 = tof32(((const half4v*)curH)[o4]);
        ((float4v*)dstF)[o4] = acc;              // e2 (fp32) for layer 3
        ((float4v*)out)[o4]  = e0 + e1 + acc;    // partial sum e0+e1+e2
    } else {
        float4v pv = ((const float4v*)out)[o4];
        ((float4v*)out)[o4] = 0.25f * (pv + acc);
    }
}

extern "C" void kernel_launch(void* const* d_in, const int* in_sizes, int n_in,
                              void* d_out, int out_size, void* d_ws, size_t ws_size,
                              hipStream_t stream) {
    const float* user_emb = (const float*)d_in[0];
    const float* item_emb = (const float*)d_in[1];
    const int*   edge_user = (const int*)d_in[2];
    const int*   edge_item = (const int*)d_in[3];
    const int*   s_row = (const int*)d_in[4];
    const int*   s_col = (const int*)d_in[5];
    const float* s_val = (const float*)d_in[6];
    float* out = (float*)d_out;

    const int U = in_sizes[0] / EMB_D;
    const int I = in_sizes[1] / EMB_D;
    const int M = U + I;
    const int E = in_sizes[2];
    const int S = in_sizes[4];
    const long MD = (long)M * EMB_D;
    const long NT = 2L * E + S;             // merged CSR entries
    const int NC = (M + CMASK) >> CSHIFT;   // number of row classes

    // workspace carve-up, 16B-aligned chunks
    char* p = (char*)d_ws;
    auto carve = [&](long bytes) {
        char* q = p;
        p += (bytes + 15) & ~15L;
        return q;
    };
    _Float16* cur0H  = (_Float16*)carve(MD * sizeof(_Float16));  // e0 (fp16)
    _Float16* cur1H  = (_Float16*)carve(MD * sizeof(_Float16));  // e1 (fp16)
    // bufC (e2, fp32) aliases the bucket array: bucket dead before e2 written
    long aliasBytes = MD * sizeof(float) > (NT + 8) * (long)sizeof(int2)
                        ? MD * sizeof(float) : (NT + 8) * (long)sizeof(int2);
    char* aliasRgn = carve(aliasBytes);
    float* bufC  = (float*)aliasRgn;
    int2*  bent  = (int2*)aliasRgn;
    float* norm    = (float*)carve((long)M * sizeof(float));
    int*   deg_all = (int*)carve((long)(M + I) * sizeof(int));   // deg | degs adjacent
    int*   deg     = deg_all;
    int*   degs    = deg_all + M;
    int*   incl    = (int*)carve((long)M * sizeof(int));
    int*   rowptr  = (int*)carve((long)(M + 1) * sizeof(int));
    int*   bsum    = (int*)carve(256 * sizeof(int));
    int*   bkcur   = (int*)carve((long)MAXC * CPAD * sizeof(int));
    int*   bkptr   = (int*)carve((long)(MAXC + 1) * sizeof(int));
    int2*  ent     = (int2*)carve((NT + 8) * sizeof(int2));

    const int nb1 = (M + 1023) / 1024;
    const int nbE = (E + 255) / 256;
    const int nbS = (S + 255) / 256;
    const int nbMax = (nbE > nbS) ? nbE : nbS;
    const int nbE2 = (E + 511) / 512;       // bin blocks (512 edges each)
    const int nbS2 = (S + 511) / 512;

    // 1) fused partitioned degrees
    hipMemsetAsync(deg_all, 0, (size_t)(M + I) * sizeof(int), stream);
    deg_part_kernel<<<NCLS * nbMax, 256, 0, stream>>>(edge_user, edge_item, E, U,
                                                      s_row, S, M, deg, degs);

    // 2) single scan over combined row lengths (also emits norm)
    scan_block<<<nb1, 1024, 0, stream>>>(deg, degs, U, M, norm, incl, bsum);
    scan_bsum<<<1, 256, 0, stream>>>(bsum, nb1);
    finalize_rowptr<<<(M + 256) / 256, 256, 0, stream>>>(incl, deg, degs, bsum, U, M, NC,
                                                         rowptr, bkcur, bkptr);

    // 3) two-pass CSR build: dense bucket append, then per-class LDS scatter
    bin_kernel<<<nbE2 + nbS2, 256, 0, stream>>>(edge_user, edge_item, E, nbE2,
                                                s_row, s_col, s_val, S,
                                                U, norm, bkcur, bent);
    csr_scatter<<<NC, 1024, 0, stream>>>(rowptr, bkptr, bent, ent, M);

    // 4) init cur0 (fp16)
    init_kernel<<<2048, 256, 0, stream>>>((const float4v*)user_emb, (const float4v*)item_emb,
                                          (long)U * (EMB_D / 4), MD / 4, (half4v*)cur0H);

    // 5) L=3 gather layers: fp16 reads for layers 1-2, fp32 for layer 3
    const int gblocks = (int)(((long)M * 16 + 255) / 256);
    gather_kernel<0><<<gblocks, 256, 0, stream>>>(rowptr, ent, cur0H, nullptr, nullptr,
                                                  cur1H, nullptr, nullptr, U, I, M);
    gather_kernel<1><<<gblocks, 256, 0, stream>>>(rowptr, ent, cur1H, nullptr, cur0H,
                                                  nullptr, bufC, out, U, I, M);
    gather_kernel<2><<<gblocks, 256, 0, stream>>>(rowptr, ent, nullptr, bufC, nullptr,
                                                  nullptr, nullptr, out, U, I, M);
}

// Round 13
// 412.059 us; speedup vs baseline: 7.5752x; 1.0418x over previous
//
#include <hip/hip_runtime.h>
#include <type_traits>

#define EMB_D 64
#define CSHIFT 9    // class = row >> 9 (512 rows/class)
#define CROWS  (1 << CSHIFT)
#define CMASK  (CROWS - 1)
#define MAXC 384    // max classes (M <= 196608; col fits 18 bits)
#define CPAD 16     // padded counters: one per 64B line
#define SFLAG (1 << 27)

typedef float    float4v __attribute__((ext_vector_type(4)));
typedef _Float16 half4v  __attribute__((ext_vector_type(4)));

__device__ inline float4v tof32(half4v v)  { return __builtin_convertvector(v, float4v); }
__device__ inline float4v tof32(float4v v) { return v; }

// ---------------------------------------------------------------------------
// class_cnt: per-class entry counts. 512 edges/block, LDS histogram ->
// one padded global atomicAdd per (block, class). The ONLY global-atomic
// pass in the pipeline, at class granularity (293 padded lines).
// ---------------------------------------------------------------------------
__global__ void __launch_bounds__(256) class_cnt(const int* __restrict__ eu,
                                                 const int* __restrict__ ei,
                                                 int E, int nbE,
                                                 const int* __restrict__ sr, int S,
                                                 int U, int* __restrict__ ctot) {
    __shared__ int hist[MAXC];
    for (int t = threadIdx.x; t < MAXC; t += 256) hist[t] = 0;
    __syncthreads();
    int blk = blockIdx.x;
    if (blk < nbE) {
        int e = blk * 512 + threadIdx.x;
        if (e < E) {
            atomicAdd(&hist[eu[e] >> CSHIFT], 1);
            atomicAdd(&hist[(U + ei[e]) >> CSHIFT], 1);
        }
        e += 256;
        if (e < E) {
            atomicAdd(&hist[eu[e] >> CSHIFT], 1);
            atomicAdd(&hist[(U + ei[e]) >> CSHIFT], 1);
        }
    } else {
        int e = (blk - nbE) * 512 + threadIdx.x;
        if (e < S) atomicAdd(&hist[(U + sr[e]) >> CSHIFT], 1);
        e += 256;
        if (e < S) atomicAdd(&hist[(U + sr[e]) >> CSHIFT], 1);
    }
    __syncthreads();
    for (int t = threadIdx.x; t < MAXC; t += 256) {
        int h = hist[t];
        if (h) atomicAdd(&ctot[t * CPAD], h);
    }
}

// ---------------------------------------------------------------------------
// class_scan: 1-block exclusive scan over NC class totals -> bkptr;
// also re-initializes ctot[c*CPAD] as the bin-pass bucket cursor.
// ---------------------------------------------------------------------------
__global__ void __launch_bounds__(512) class_scan(int* __restrict__ ctot, int NC,
                                                  int* __restrict__ bkptr) {
    __shared__ int sh[512];
    int t = threadIdx.x;
    int v = (t < NC) ? ctot[t * CPAD] : 0;
    sh[t] = v;
    __syncthreads();
    for (int ofs = 1; ofs < 512; ofs <<= 1) {
        int x = (t >= ofs) ? sh[t - ofs] : 0;
        __syncthreads();
        sh[t] += x;
        __syncthreads();
    }
    int excl = sh[t] - v;
    if (t < NC) {
        bkptr[t] = excl;
        ctot[t * CPAD] = excl;   // becomes bucket append cursor
    }
    if (t == 511) bkptr[NC] = sh[511];
}

// ---------------------------------------------------------------------------
// bin: append entries into per-class buckets (weight-free). 512 edges/block,
// LDS histogram -> one padded global atomicAdd per (block, class) ->
// contiguous per-block chunks (dense writes, ~1x amplification).
// Entry .x = (sflag<<27) | (row_lo<<18) | col ; .y = sv bits (s) or 0 (bip).
// ---------------------------------------------------------------------------
__global__ void __launch_bounds__(256) bin_kernel(const int* __restrict__ eu,
                                                  const int* __restrict__ ei,
                                                  int E, int nbE,
                                                  const int* __restrict__ sr,
                                                  const int* __restrict__ sc,
                                                  const float* __restrict__ sv, int S,
                                                  int U,
                                                  int* __restrict__ bkcur,
                                                  int2* __restrict__ bent) {
    __shared__ int hist[MAXC];
    __shared__ int base[MAXC];
    for (int t = threadIdx.x; t < MAXC; t += 256) hist[t] = 0;
    __syncthreads();

    int blk = blockIdx.x;
    int c0 = -1, c1 = -1, c2 = -1, c3 = -1;
    int2 v0, v1, v2, v3;
    if (blk < nbE) {
        {
            int e = blk * 512 + threadIdx.x;
            if (e < E) {
                int u  = eu[e];
                int iv = U + ei[e];
                c0 = u >> CSHIFT;  v0 = make_int2(((u & CMASK) << 18) | iv, 0);
                c1 = iv >> CSHIFT; v1 = make_int2(((iv & CMASK) << 18) | u, 0);
                atomicAdd(&hist[c0], 1);
                atomicAdd(&hist[c1], 1);
            }
        }
        {
            int e = blk * 512 + 256 + threadIdx.x;
            if (e < E) {
                int u  = eu[e];
                int iv = U + ei[e];
                c2 = u >> CSHIFT;  v2 = make_int2(((u & CMASK) << 18) | iv, 0);
                c3 = iv >> CSHIFT; v3 = make_int2(((iv & CMASK) << 18) | u, 0);
                atomicAdd(&hist[c2], 1);
                atomicAdd(&hist[c3], 1);
            }
        }
    } else {
        {
            int e = (blk - nbE) * 512 + threadIdx.x;
            if (e < S) {
                int dst = U + sr[e];
                c0 = dst >> CSHIFT;
                v0 = make_int2(SFLAG | ((dst & CMASK) << 18) | (U + sc[e]),
                               __float_as_int(sv[e]));
                atomicAdd(&hist[c0], 1);
            }
        }
        {
            int e = (blk - nbE) * 512 + 256 + threadIdx.x;
            if (e < S) {
                int dst = U + sr[e];
                c1 = dst >> CSHIFT;
                v1 = make_int2(SFLAG | ((dst & CMASK) << 18) | (U + sc[e]),
                               __float_as_int(sv[e]));
                atomicAdd(&hist[c1], 1);
            }
        }
    }
    __syncthreads();
    for (int t = threadIdx.x; t < MAXC; t += 256) {
        int h = hist[t];
        base[t] = h ? atomicAdd(&bkcur[t * CPAD], h) : 0;
        hist[t] = 0;
    }
    __syncthreads();
    if (c0 >= 0) { int o = atomicAdd(&hist[c0], 1); bent[base[c0] + o] = v0; }
    if (c1 >= 0) { int o = atomicAdd(&hist[c1], 1); bent[base[c1] + o] = v1; }
    if (c2 >= 0) { int o = atomicAdd(&hist[c2], 1); bent[base[c2] + o] = v2; }
    if (c3 >= 0) { int o = atomicAdd(&hist[c3], 1); bent[base[c3] + o] = v3; }
}

// ---------------------------------------------------------------------------
// scatter_cls: one 1024-thread block per 512-row class. From its bucket:
// (1) LDS histograms: bip-degree + total per row -> norm = rsqrt(bipdeg+1),
// (2) LDS scan -> rowptr + cursors (no global row atomics anywhere),
// (3) re-stream bucket (L2-hot) -> exact CSR into the exclusively-owned
//     ~window (single XCD, temporally dense -> ~1x write amplification).
// Bip entries store (col, row|0x80000000) for the later weight fill.
// ---------------------------------------------------------------------------
__global__ void __launch_bounds__(1024) scatter_cls(const int* __restrict__ bkptr,
                                                    const int2* __restrict__ bent,
                                                    float* __restrict__ norm,
                                                    int* __restrict__ rowptr,
                                                    int2* __restrict__ ent, int M) {
    __shared__ int cntb[CROWS];
    __shared__ int cntt[CROWS];
    __shared__ int cur[CROWS];
    int c   = blockIdx.x;
    int rlo = c << CSHIFT;
    int nrows = min(CROWS, M - rlo);
    if (threadIdx.x < CROWS) {
        cntb[threadIdx.x] = 0;
        cntt[threadIdx.x] = 0;
    }
    __syncthreads();

    int beg = bkptr[c], end = bkptr[c + 1];
    for (int k = beg + threadIdx.x; k < end; k += 1024) {
        int x = bent[k].x;
        int rl = (x >> 18) & CMASK;
        atomicAdd(&cntt[rl], 1);
        if (!(x & SFLAG)) atomicAdd(&cntb[rl], 1);
    }
    __syncthreads();

    int my = 0;
    if (threadIdx.x < CROWS) {
        my = cntt[threadIdx.x];
        if (threadIdx.x < nrows)
            norm[rlo + threadIdx.x] = rsqrtf((float)cntb[threadIdx.x] + 1.0f);
    }
    // LDS inclusive scan of cntt (512 lanes)
    for (int ofs = 1; ofs < CROWS; ofs <<= 1) {
        int x = (threadIdx.x >= ofs && threadIdx.x < CROWS) ? cntt[threadIdx.x - ofs] : 0;
        __syncthreads();
        if (threadIdx.x < CROWS) cntt[threadIdx.x] += x;
        __syncthreads();
    }
    if (threadIdx.x < CROWS) {
        int v = beg + cntt[threadIdx.x] - my;   // exclusive
        if (threadIdx.x < nrows) rowptr[rlo + threadIdx.x] = v;
        cur[threadIdx.x] = v;
    }
    if (threadIdx.x == 0) rowptr[rlo + nrows] = end;  // covers rowptr[M]
    __syncthreads();

    for (int k = beg + threadIdx.x; k < end; k += 1024) {
        int2 e = bent[k];
        int rl  = (e.x >> 18) & CMASK;
        int col = e.x & 0x3FFFF;
        int p = atomicAdd(&cur[rl], 1);
        ent[p] = (e.x & SFLAG) ? make_int2(col, e.y)
                               : make_int2(col, (rlo + rl) | (int)0x80000000);
    }
}

// ---------------------------------------------------------------------------
// fill_w: sequential pass over ent; bip entries (.y sign bit set) get
// w = norm[row]*norm[col] (bit-identical product to the original formula).
// ---------------------------------------------------------------------------
__global__ void __launch_bounds__(256) fill_w(const float* __restrict__ norm,
                                              int2* __restrict__ ent, int NT) {
    int k = blockIdx.x * 256 + threadIdx.x;
    if (k >= NT) return;
    int2 e = ent[k];
    if (e.y < 0) {
        int row = e.y & 0x7FFFFFFF;
        e.y = __float_as_int(norm[row] * norm[e.x]);
        ent[k] = e;
    }
}

// ---------------------------------------------------------------------------
// cur0 (fp16) = concat(user_emb, item_emb)
// ---------------------------------------------------------------------------
__global__ void init_kernel(const float4v* __restrict__ ue, const float4v* __restrict__ ie,
                            long u4, long total4, half4v* __restrict__ curH) {
    long stride = (long)gridDim.x * blockDim.x;
    for (long idx = (long)blockIdx.x * blockDim.x + threadIdx.x; idx < total4; idx += stride) {
        float4v v = (idx < u4) ? ue[idx] : ie[idx - u4];
        curH[idx] = __builtin_convertvector(v, half4v);
    }
}

// ---------------------------------------------------------------------------
// gather: ONE 16-lane quarter-wave per destination row (4 rows per wave),
// 4-deep masked software pipeline -> 16 outstanding row loads per wave.
// Heavy-first: item rows dispatched first, users fill the tail.
// MODE 0: read fp16 curH -> write fp16 dstH          (e0 -> e1)
// MODE 1: read fp16 curH -> dstF=e2 (fp32), out = e0+e1+e2
// MODE 2: read fp32 curF -> out = 0.25*(out + e3)
// ---------------------------------------------------------------------------
template <int MODE>
__global__ void __launch_bounds__(256) gather_kernel(const int* __restrict__ rowptr,
                                                     const int2* __restrict__ ent,
                                                     const _Float16* __restrict__ curH,
                                                     const float* __restrict__ curF,
                                                     const _Float16* __restrict__ cur0H,
                                                     _Float16* __restrict__ dstH,
                                                     float* __restrict__ dstF,
                                                     float* __restrict__ out,
                                                     int U, int I, int M) {
    using VecT = typename std::conditional<MODE == 2, float4v, half4v>::type;
    int raw = (int)((((long)blockIdx.x * blockDim.x) + threadIdx.x) >> 4);
    int l   = threadIdx.x & 15;
    if (raw >= M) return;
    int row = (raw < I) ? (U + raw) : (raw - I);
    int beg = rowptr[row];
    int end = rowptr[row + 1];
    const VecT* curv = (MODE == 2) ? (const VecT*)(const void*)curF
                                   : (const VecT*)(const void*)curH;

    float4v acc = {0.f, 0.f, 0.f, 0.f};
    int j = beg;
    int2 a0 = (j + 0 < end) ? ent[j + 0] : make_int2(0, 0);
    int2 a1 = (j + 1 < end) ? ent[j + 1] : make_int2(0, 0);
    int2 a2 = (j + 2 < end) ? ent[j + 2] : make_int2(0, 0);
    int2 a3 = (j + 3 < end) ? ent[j + 3] : make_int2(0, 0);
    VecT v0 = curv[(long)a0.x * 16 + l];
    VecT v1 = curv[(long)a1.x * 16 + l];
    VecT v2 = curv[(long)a2.x * 16 + l];
    VecT v3 = curv[(long)a3.x * 16 + l];
    while (j + 4 < end) {
        int jn = j + 4;
        int2 b0 = (jn + 0 < end) ? ent[jn + 0] : make_int2(0, 0);
        int2 b1 = (jn + 1 < end) ? ent[jn + 1] : make_int2(0, 0);
        int2 b2 = (jn + 2 < end) ? ent[jn + 2] : make_int2(0, 0);
        int2 b3 = (jn + 3 < end) ? ent[jn + 3] : make_int2(0, 0);
        VecT u0 = curv[(long)b0.x * 16 + l];
        VecT u1 = curv[(long)b1.x * 16 + l];
        VecT u2 = curv[(long)b2.x * 16 + l];
        VecT u3 = curv[(long)b3.x * 16 + l];
        acc += __int_as_float(a0.y) * tof32(v0);
        acc += __int_as_float(a1.y) * tof32(v1);
        acc += __int_as_float(a2.y) * tof32(v2);
        acc += __int_as_float(a3.y) * tof32(v3);
        a0 = b0; a1 = b1; a2 = b2; a3 = b3;
        v0 = u0; v1 = u1; v2 = u2; v3 = u3;
        j = jn;
    }
    acc += __int_as_float(a0.y) * tof32(v0);
    acc += __int_as_float(a1.y) * tof32(v1);
    acc += __int_as_float(a2.y) * tof32(v2);
    acc += __int_as_float(a3.y) * tof32(v3);

    long o4 = (long)row * 16 + l;
    if (MODE == 0) {
        ((half4v*)dstH)[o4] = __builtin_convertvector(acc, half4v);
    } else if (MODE == 1) {
        float4v e0 = tof32(((const half4v*)cur0H)[o4]);
        float4v e1 = tof32(((const half4v*)curH)[o4]);
        ((float4v*)dstF)[o4] = acc;              // e2 (fp32) for layer 3
        ((float4v*)out)[o4]  = e0 + e1 + acc;    // partial sum e0+e1+e2
    } else {
        float4v pv = ((const float4v*)out)[o4];
        ((float4v*)out)[o4] = 0.25f * (pv + acc);
    }
}

extern "C" void kernel_launch(void* const* d_in, const int* in_sizes, int n_in,
                              void* d_out, int out_size, void* d_ws, size_t ws_size,
                              hipStream_t stream) {
    const float* user_emb = (const float*)d_in[0];
    const float* item_emb = (const float*)d_in[1];
    const int*   edge_user = (const int*)d_in[2];
    const int*   edge_item = (const int*)d_in[3];
    const int*   s_row = (const int*)d_in[4];
    const int*   s_col = (const int*)d_in[5];
    const float* s_val = (const float*)d_in[6];
    float* out = (float*)d_out;

    const int U = in_sizes[0] / EMB_D;
    const int I = in_sizes[1] / EMB_D;
    const int M = U + I;
    const int E = in_sizes[2];
    const int S = in_sizes[4];
    const long MD = (long)M * EMB_D;
    const long NT = 2L * E + S;             // merged CSR entries
    const int NC = (M + CMASK) >> CSHIFT;   // number of row classes

    // workspace carve-up, 16B-aligned chunks
    char* p = (char*)d_ws;
    auto carve = [&](long bytes) {
        char* q = p;
        p += (bytes + 15) & ~15L;
        return q;
    };
    _Float16* cur0H  = (_Float16*)carve(MD * sizeof(_Float16));  // e0 (fp16)
    _Float16* cur1H  = (_Float16*)carve(MD * sizeof(_Float16));  // e1 (fp16)
    // bufC (e2, fp32) aliases the bucket array: bucket dead before e2 written
    long aliasBytes = MD * sizeof(float) > (NT + 8) * (long)sizeof(int2)
                        ? MD * sizeof(float) : (NT + 8) * (long)sizeof(int2);
    char* aliasRgn = carve(aliasBytes);
    float* bufC  = (float*)aliasRgn;
    int2*  bent  = (int2*)aliasRgn;
    float* norm   = (float*)carve((long)M * sizeof(float));
    int*   rowptr = (int*)carve((long)(M + 1) * sizeof(int));
    int*   ctot   = (int*)carve((long)MAXC * CPAD * sizeof(int)); // counters/cursors
    int*   bkptr  = (int*)carve((long)(MAXC + 1) * sizeof(int));
    int2*  ent    = (int2*)carve((NT + 8) * sizeof(int2));

    const int nbE2 = (E + 511) / 512;       // 512 edges per block
    const int nbS2 = (S + 511) / 512;

    // 1) per-class counts (LDS-aggregated, padded class counters)
    hipMemsetAsync(ctot, 0, (size_t)MAXC * CPAD * sizeof(int), stream);
    class_cnt<<<nbE2 + nbS2, 256, 0, stream>>>(edge_user, edge_item, E, nbE2,
                                               s_row, S, U, ctot);

    // 2) class scan -> bkptr; ctot becomes the bin append cursor
    class_scan<<<1, 512, 0, stream>>>(ctot, NC, bkptr);

    // 3) bin entries into class buckets (dense appends, weight-free)
    bin_kernel<<<nbE2 + nbS2, 256, 0, stream>>>(edge_user, edge_item, E, nbE2,
                                                s_row, s_col, s_val, S,
                                                U, ctot, bent);

    // 4) per-class: degrees->norm, scan->rowptr, scatter->CSR (all in LDS)
    scatter_cls<<<NC, 1024, 0, stream>>>(bkptr, bent, norm, rowptr, ent, M);

    // 5) weight fill for bip entries
    fill_w<<<(int)((NT + 255) / 256), 256, 0, stream>>>(norm, ent, (int)NT);

    // 6) init cur0 (fp16)
    init_kernel<<<2048, 256, 0, stream>>>((const float4v*)user_emb, (const float4v*)item_emb,
                                          (long)U * (EMB_D / 4), MD / 4, (half4v*)cur0H);

    // 7) L=3 gather layers: fp16 reads for layers 1-2, fp32 for layer 3
    const int gblocks = (int)(((long)M * 16 + 255) / 256);
    gather_kernel<0><<<gblocks, 256, 0, stream>>>(rowptr, ent, cur0H, nullptr, nullptr,
                                                  cur1H, nullptr, nullptr, U, I, M);
    gather_kernel<1><<<gblocks, 256, 0, stream>>>(rowptr, ent, cur1H, nullptr, cur0H,
                                                  nullptr, bufC, out, U, I, M);
    gather_kernel<2><<<gblocks, 256, 0, stream>>>(rowptr, ent, nullptr, bufC, nullptr,
                                                  nullptr, nullptr, out, U, I, M);
}

// Round 14
// 307.036 us; speedup vs baseline: 10.1663x; 1.3421x over previous
//
#include <hip/hip_runtime.h>
#include <type_traits>

#define EMB_D 64
#define CSHIFT 9    // class = row >> 9 (512 rows/class)
#define CROWS  (1 << CSHIFT)
#define CMASK  (CROWS - 1)
#define MAXC 384    // max classes (M <= 196608; col fits 18 bits)
#define CPAD 16     // padded counters: one per 64B line
#define SFLAG (1 << 27)
#define EPB 4096    // edges per bin/count block (16 per thread)

typedef float    float4v __attribute__((ext_vector_type(4)));
typedef _Float16 half4v  __attribute__((ext_vector_type(4)));

__device__ inline float4v tof32(half4v v)  { return __builtin_convertvector(v, float4v); }
__device__ inline float4v tof32(float4v v) { return v; }

// ---------------------------------------------------------------------------
// class_cnt: per-class entry counts. EPB edges/block, LDS histogram ->
// one padded global atomicAdd per (block, class). ~368 blocks total.
// ---------------------------------------------------------------------------
__global__ void __launch_bounds__(256) class_cnt(const int* __restrict__ eu,
                                                 const int* __restrict__ ei,
                                                 int E, int nbE,
                                                 const int* __restrict__ sr, int S,
                                                 int U, int* __restrict__ ctot) {
    __shared__ int hist[MAXC];
    for (int t = threadIdx.x; t < MAXC; t += 256) hist[t] = 0;
    __syncthreads();
    int blk = blockIdx.x;
    if (blk < nbE) {
        int e0 = blk * EPB, e1 = min(e0 + EPB, E);
        for (int e = e0 + threadIdx.x; e < e1; e += 256) {
            atomicAdd(&hist[eu[e] >> CSHIFT], 1);
            atomicAdd(&hist[(U + ei[e]) >> CSHIFT], 1);
        }
    } else {
        int e0 = (blk - nbE) * EPB, e1 = min(e0 + EPB, S);
        for (int e = e0 + threadIdx.x; e < e1; e += 256) {
            atomicAdd(&hist[(U + sr[e]) >> CSHIFT], 1);
        }
    }
    __syncthreads();
    for (int t = threadIdx.x; t < MAXC; t += 256) {
        int h = hist[t];
        if (h) atomicAdd(&ctot[t * CPAD], h);
    }
}

// ---------------------------------------------------------------------------
// class_scan: 1-block exclusive scan over NC class totals -> bkptr;
// also re-initializes ctot[c*CPAD] as the bin-pass bucket cursor.
// ---------------------------------------------------------------------------
__global__ void __launch_bounds__(512) class_scan(int* __restrict__ ctot, int NC,
                                                  int* __restrict__ bkptr) {
    __shared__ int sh[512];
    int t = threadIdx.x;
    int v = (t < NC) ? ctot[t * CPAD] : 0;
    sh[t] = v;
    __syncthreads();
    for (int ofs = 1; ofs < 512; ofs <<= 1) {
        int x = (t >= ofs) ? sh[t - ofs] : 0;
        __syncthreads();
        sh[t] += x;
        __syncthreads();
    }
    int excl = sh[t] - v;
    if (t < NC) {
        bkptr[t] = excl;
        ctot[t * CPAD] = excl;   // becomes bucket append cursor
    }
    if (t == 511) bkptr[NC] = sh[511];
}

// ---------------------------------------------------------------------------
// bin: append entries into per-class buckets (weight-free). EPB edges/block,
// two-phase: (A) LDS-histogram count -> one padded global atomicAdd per
// (block, class) reserves a CONTIGUOUS ~28-entry chunk; (B) re-read the
// edge range (L2-hot) and append. Big chunks -> lines mostly filled by one
// block -> ~1.3x write amplification (vs 2.8x at 512 edges/block).
// Entry .x = (sflag<<27) | (row_lo<<18) | col ; .y = sv bits (s) or 0 (bip).
// ---------------------------------------------------------------------------
__global__ void __launch_bounds__(256) bin_kernel(const int* __restrict__ eu,
                                                  const int* __restrict__ ei,
                                                  int E, int nbE,
                                                  const int* __restrict__ sr,
                                                  const int* __restrict__ sc,
                                                  const float* __restrict__ sv, int S,
                                                  int U,
                                                  int* __restrict__ bkcur,
                                                  int2* __restrict__ bent) {
    __shared__ int hist[MAXC];
    __shared__ int base[MAXC];
    for (int t = threadIdx.x; t < MAXC; t += 256) hist[t] = 0;
    __syncthreads();

    int blk = blockIdx.x;
    if (blk < nbE) {
        int e0 = blk * EPB, e1 = min(e0 + EPB, E);
        // phase A: count
        for (int e = e0 + threadIdx.x; e < e1; e += 256) {
            atomicAdd(&hist[eu[e] >> CSHIFT], 1);
            atomicAdd(&hist[(U + ei[e]) >> CSHIFT], 1);
        }
        __syncthreads();
        for (int t = threadIdx.x; t < MAXC; t += 256) {
            int h = hist[t];
            base[t] = h ? atomicAdd(&bkcur[t * CPAD], h) : 0;
            hist[t] = 0;
        }
        __syncthreads();
        // phase B: append (edge range L2-hot from phase A)
        for (int e = e0 + threadIdx.x; e < e1; e += 256) {
            int u  = eu[e];
            int iv = U + ei[e];
            int c0 = u >> CSHIFT, c1 = iv >> CSHIFT;
            int o0 = atomicAdd(&hist[c0], 1);
            bent[base[c0] + o0] = make_int2(((u & CMASK) << 18) | iv, 0);
            int o1 = atomicAdd(&hist[c1], 1);
            bent[base[c1] + o1] = make_int2(((iv & CMASK) << 18) | u, 0);
        }
    } else {
        int e0 = (blk - nbE) * EPB, e1 = min(e0 + EPB, S);
        for (int e = e0 + threadIdx.x; e < e1; e += 256) {
            atomicAdd(&hist[(U + sr[e]) >> CSHIFT], 1);
        }
        __syncthreads();
        for (int t = threadIdx.x; t < MAXC; t += 256) {
            int h = hist[t];
            base[t] = h ? atomicAdd(&bkcur[t * CPAD], h) : 0;
            hist[t] = 0;
        }
        __syncthreads();
        for (int e = e0 + threadIdx.x; e < e1; e += 256) {
            int dst = U + sr[e];
            int c = dst >> CSHIFT;
            int o = atomicAdd(&hist[c], 1);
            bent[base[c] + o] = make_int2(SFLAG | ((dst & CMASK) << 18) | (U + sc[e]),
                                          __float_as_int(sv[e]));
        }
    }
}

// ---------------------------------------------------------------------------
// scatter_cls: one 1024-thread block per 512-row class. From its bucket:
// (1) LDS histograms: bip-degree + total per row -> norm = rsqrt(bipdeg+1),
// (2) LDS scan -> rowptr + cursors (no global row atomics anywhere),
// (3) re-stream bucket (L2-hot) -> exact CSR into the exclusively-owned
//     window (single XCD, temporally dense -> ~1x write amplification).
// Bip entries store (col, row|0x80000000) for the later weight fill.
// ---------------------------------------------------------------------------
__global__ void __launch_bounds__(1024) scatter_cls(const int* __restrict__ bkptr,
                                                    const int2* __restrict__ bent,
                                                    float* __restrict__ norm,
                                                    int* __restrict__ rowptr,
                                                    int2* __restrict__ ent, int M) {
    __shared__ int cntb[CROWS];
    __shared__ int cntt[CROWS];
    __shared__ int cur[CROWS];
    int c   = blockIdx.x;
    int rlo = c << CSHIFT;
    int nrows = min(CROWS, M - rlo);
    if (threadIdx.x < CROWS) {
        cntb[threadIdx.x] = 0;
        cntt[threadIdx.x] = 0;
    }
    __syncthreads();

    int beg = bkptr[c], end = bkptr[c + 1];
    for (int k = beg + threadIdx.x; k < end; k += 1024) {
        int x = bent[k].x;
        int rl = (x >> 18) & CMASK;
        atomicAdd(&cntt[rl], 1);
        if (!(x & SFLAG)) atomicAdd(&cntb[rl], 1);
    }
    __syncthreads();

    int my = 0;
    if (threadIdx.x < CROWS) {
        my = cntt[threadIdx.x];
        if (threadIdx.x < nrows)
            norm[rlo + threadIdx.x] = rsqrtf((float)cntb[threadIdx.x] + 1.0f);
    }
    // LDS inclusive scan of cntt (512 lanes)
    for (int ofs = 1; ofs < CROWS; ofs <<= 1) {
        int x = (threadIdx.x >= ofs && threadIdx.x < CROWS) ? cntt[threadIdx.x - ofs] : 0;
        __syncthreads();
        if (threadIdx.x < CROWS) cntt[threadIdx.x] += x;
        __syncthreads();
    }
    if (threadIdx.x < CROWS) {
        int v = beg + cntt[threadIdx.x] - my;   // exclusive
        if (threadIdx.x < nrows) rowptr[rlo + threadIdx.x] = v;
        cur[threadIdx.x] = v;
    }
    if (threadIdx.x == 0) rowptr[rlo + nrows] = end;  // covers rowptr[M]
    __syncthreads();

    for (int k = beg + threadIdx.x; k < end; k += 1024) {
        int2 e = bent[k];
        int rl  = (e.x >> 18) & CMASK;
        int col = e.x & 0x3FFFF;
        int p = atomicAdd(&cur[rl], 1);
        ent[p] = (e.x & SFLAG) ? make_int2(col, e.y)
                               : make_int2(col, (rlo + rl) | (int)0x80000000);
    }
}

// ---------------------------------------------------------------------------
// fill_w: sequential pass over ent; bip entries (.y sign bit set) get
// w = norm[row]*norm[col] (bit-identical product to the original formula).
// ---------------------------------------------------------------------------
__global__ void __launch_bounds__(256) fill_w(const float* __restrict__ norm,
                                              int2* __restrict__ ent, int NT) {
    int k = blockIdx.x * 256 + threadIdx.x;
    if (k >= NT) return;
    int2 e = ent[k];
    if (e.y < 0) {
        int row = e.y & 0x7FFFFFFF;
        e.y = __float_as_int(norm[row] * norm[e.x]);
        ent[k] = e;
    }
}

// ---------------------------------------------------------------------------
// cur0 (fp16) = concat(user_emb, item_emb)
// ---------------------------------------------------------------------------
__global__ void init_kernel(const float4v* __restrict__ ue, const float4v* __restrict__ ie,
                            long u4, long total4, half4v* __restrict__ curH) {
    long stride = (long)gridDim.x * blockDim.x;
    for (long idx = (long)blockIdx.x * blockDim.x + threadIdx.x; idx < total4; idx += stride) {
        float4v v = (idx < u4) ? ue[idx] : ie[idx - u4];
        curH[idx] = __builtin_convertvector(v, half4v);
    }
}

// ---------------------------------------------------------------------------
// gather: ONE 16-lane quarter-wave per destination row (4 rows per wave),
// 4-deep masked software pipeline -> 16 outstanding row loads per wave.
// Heavy-first: item rows dispatched first, users fill the tail.
// MODE 0: read fp16 curH -> write fp16 dstH          (e0 -> e1)
// MODE 1: read fp16 curH -> dstF=e2 (fp32), out = e0+e1+e2
// MODE 2: read fp32 curF -> out = 0.25*(out + e3)
// ---------------------------------------------------------------------------
template <int MODE>
__global__ void __launch_bounds__(256) gather_kernel(const int* __restrict__ rowptr,
                                                     const int2* __restrict__ ent,
                                                     const _Float16* __restrict__ curH,
                                                     const float* __restrict__ curF,
                                                     const _Float16* __restrict__ cur0H,
                                                     _Float16* __restrict__ dstH,
                                                     float* __restrict__ dstF,
                                                     float* __restrict__ out,
                                                     int U, int I, int M) {
    using VecT = typename std::conditional<MODE == 2, float4v, half4v>::type;
    int raw = (int)((((long)blockIdx.x * blockDim.x) + threadIdx.x) >> 4);
    int l   = threadIdx.x & 15;
    if (raw >= M) return;
    int row = (raw < I) ? (U + raw) : (raw - I);
    int beg = rowptr[row];
    int end = rowptr[row + 1];
    const VecT* curv = (MODE == 2) ? (const VecT*)(const void*)curF
                                   : (const VecT*)(const void*)curH;

    float4v acc = {0.f, 0.f, 0.f, 0.f};
    int j = beg;
    int2 a0 = (j + 0 < end) ? ent[j + 0] : make_int2(0, 0);
    int2 a1 = (j + 1 < end) ? ent[j + 1] : make_int2(0, 0);
    int2 a2 = (j + 2 < end) ? ent[j + 2] : make_int2(0, 0);
    int2 a3 = (j + 3 < end) ? ent[j + 3] : make_int2(0, 0);
    VecT v0 = curv[(long)a0.x * 16 + l];
    VecT v1 = curv[(long)a1.x * 16 + l];
    VecT v2 = curv[(long)a2.x * 16 + l];
    VecT v3 = curv[(long)a3.x * 16 + l];
    while (j + 4 < end) {
        int jn = j + 4;
        int2 b0 = (jn + 0 < end) ? ent[jn + 0] : make_int2(0, 0);
        int2 b1 = (jn + 1 < end) ? ent[jn + 1] : make_int2(0, 0);
        int2 b2 = (jn + 2 < end) ? ent[jn + 2] : make_int2(0, 0);
        int2 b3 = (jn + 3 < end) ? ent[jn + 3] : make_int2(0, 0);
        VecT u0 = curv[(long)b0.x * 16 + l];
        VecT u1 = curv[(long)b1.x * 16 + l];
        VecT u2 = curv[(long)b2.x * 16 + l];
        VecT u3 = curv[(long)b3.x * 16 + l];
        acc += __int_as_float(a0.y) * tof32(v0);
        acc += __int_as_float(a1.y) * tof32(v1);
        acc += __int_as_float(a2.y) * tof32(v2);
        acc += __int_as_float(a3.y) * tof32(v3);
        a0 = b0; a1 = b1; a2 = b2; a3 = b3;
        v0 = u0; v1 = u1; v2 = u2; v3 = u3;
        j = jn;
    }
    acc += __int_as_float(a0.y) * tof32(v0);
    acc += __int_as_float(a1.y) * tof32(v1);
    acc += __int_as_float(a2.y) * tof32(v2);
    acc += __int_as_float(a3.y) * tof32(v3);

    long o4 = (long)row * 16 + l;
    if (MODE == 0) {
        ((half4v*)dstH)[o4] = __builtin_convertvector(acc, half4v);
    } else if (MODE == 1) {
        float4v e0 = tof32(((const half4v*)cur0H)[o4]);
        float4v e1 = tof32(((const half4v*)curH)[o4]);
        ((float4v*)dstF)[o4] = acc;              // e2 (fp32) for layer 3
        ((float4v*)out)[o4]  = e0 + e1 + acc;    // partial sum e0+e1+e2
    } else {
        float4v pv = ((const float4v*)out)[o4];
        ((float4v*)out)[o4] = 0.25f * (pv + acc);
    }
}

extern "C" void kernel_launch(void* const* d_in, const int* in_sizes, int n_in,
                              void* d_out, int out_size, void* d_ws, size_t ws_size,
                              hipStream_t stream) {
    const float* user_emb = (const float*)d_in[0];
    const float* item_emb = (const float*)d_in[1];
    const int*   edge_user = (const int*)d_in[2];
    const int*   edge_item = (const int*)d_in[3];
    const int*   s_row = (const int*)d_in[4];
    const int*   s_col = (const int*)d_in[5];
    const float* s_val = (const float*)d_in[6];
    float* out = (float*)d_out;

    const int U = in_sizes[0] / EMB_D;
    const int I = in_sizes[1] / EMB_D;
    const int M = U + I;
    const int E = in_sizes[2];
    const int S = in_sizes[4];
    const long MD = (long)M * EMB_D;
    const long NT = 2L * E + S;             // merged CSR entries
    const int NC = (M + CMASK) >> CSHIFT;   // number of row classes

    // workspace carve-up, 16B-aligned chunks
    char* p = (char*)d_ws;
    auto carve = [&](long bytes) {
        char* q = p;
        p += (bytes + 15) & ~15L;
        return q;
    };
    _Float16* cur0H  = (_Float16*)carve(MD * sizeof(_Float16));  // e0 (fp16)
    _Float16* cur1H  = (_Float16*)carve(MD * sizeof(_Float16));  // e1 (fp16)
    // bufC (e2, fp32) aliases the bucket array: bucket dead before e2 written
    long aliasBytes = MD * sizeof(float) > (NT + 8) * (long)sizeof(int2)
                        ? MD * sizeof(float) : (NT + 8) * (long)sizeof(int2);
    char* aliasRgn = carve(aliasBytes);
    float* bufC  = (float*)aliasRgn;
    int2*  bent  = (int2*)aliasRgn;
    float* norm   = (float*)carve((long)M * sizeof(float));
    int*   rowptr = (int*)carve((long)(M + 1) * sizeof(int));
    int*   ctot   = (int*)carve((long)MAXC * CPAD * sizeof(int)); // counters/cursors
    int*   bkptr  = (int*)carve((long)(MAXC + 1) * sizeof(int));
    int2*  ent    = (int2*)carve((NT + 8) * sizeof(int2));

    const int nbE2 = (E + EPB - 1) / EPB;
    const int nbS2 = (S + EPB - 1) / EPB;

    // 1) per-class counts (LDS-aggregated, padded class counters)
    hipMemsetAsync(ctot, 0, (size_t)MAXC * CPAD * sizeof(int), stream);
    class_cnt<<<nbE2 + nbS2, 256, 0, stream>>>(edge_user, edge_item, E, nbE2,
                                               s_row, S, U, ctot);

    // 2) class scan -> bkptr; ctot becomes the bin append cursor
    class_scan<<<1, 512, 0, stream>>>(ctot, NC, bkptr);

    // 3) bin entries into class buckets (two-phase, big contiguous chunks)
    bin_kernel<<<nbE2 + nbS2, 256, 0, stream>>>(edge_user, edge_item, E, nbE2,
                                                s_row, s_col, s_val, S,
                                                U, ctot, bent);

    // 4) per-class: degrees->norm, scan->rowptr, scatter->CSR (all in LDS)
    scatter_cls<<<NC, 1024, 0, stream>>>(bkptr, bent, norm, rowptr, ent, M);

    // 5) weight fill for bip entries
    fill_w<<<(int)((NT + 255) / 256), 256, 0, stream>>>(norm, ent, (int)NT);

    // 6) init cur0 (fp16)
    init_kernel<<<2048, 256, 0, stream>>>((const float4v*)user_emb, (const float4v*)item_emb,
                                          (long)U * (EMB_D / 4), MD / 4, (half4v*)cur0H);

    // 7) L=3 gather layers: fp16 reads for layers 1-2, fp32 for layer 3
    const int gblocks = (int)(((long)M * 16 + 255) / 256);
    gather_kernel<0><<<gblocks, 256, 0, stream>>>(rowptr, ent, cur0H, nullptr, nullptr,
                                                  cur1H, nullptr, nullptr, U, I, M);
    gather_kernel<1><<<gblocks, 256, 0, stream>>>(rowptr, ent, cur1H, nullptr, cur0H,
                                                  nullptr, bufC, out, U, I, M);
    gather_kernel<2><<<gblocks, 256, 0, stream>>>(rowptr, ent, nullptr, bufC, nullptr,
                                                  nullptr, nullptr, out, U, I, M);
}

// Round 15
// 274.652 us; speedup vs baseline: 11.3650x; 1.1179x over previous
//
#include <hip/hip_runtime.h>

#define EMB_D 64
#define CSHIFT 9    // class = row >> 9 (512 rows/class)
#define CROWS  (1 << CSHIFT)
#define CMASK  (CROWS - 1)
#define MAXC 384    // max classes (M <= 196608; col fits 18 bits)
#define CPAD 16     // padded counters: one per 64B line
#define SFLAG (1 << 27)
#define EPB 4096    // edges per bin/count block (16 per thread)

typedef float    float4v __attribute__((ext_vector_type(4)));
typedef _Float16 half4v  __attribute__((ext_vector_type(4)));

__device__ inline float4v tof32(half4v v)  { return __builtin_convertvector(v, float4v); }

// ---------------------------------------------------------------------------
// class_cnt: per-class entry counts. EPB edges/block, LDS histogram ->
// one padded global atomicAdd per (block, class). ~368 blocks total.
// ---------------------------------------------------------------------------
__global__ void __launch_bounds__(256) class_cnt(const int* __restrict__ eu,
                                                 const int* __restrict__ ei,
                                                 int E, int nbE,
                                                 const int* __restrict__ sr, int S,
                                                 int U, int* __restrict__ ctot) {
    __shared__ int hist[MAXC];
    for (int t = threadIdx.x; t < MAXC; t += 256) hist[t] = 0;
    __syncthreads();
    int blk = blockIdx.x;
    if (blk < nbE) {
        int e0 = blk * EPB, e1 = min(e0 + EPB, E);
        for (int e = e0 + threadIdx.x; e < e1; e += 256) {
            atomicAdd(&hist[eu[e] >> CSHIFT], 1);
            atomicAdd(&hist[(U + ei[e]) >> CSHIFT], 1);
        }
    } else {
        int e0 = (blk - nbE) * EPB, e1 = min(e0 + EPB, S);
        for (int e = e0 + threadIdx.x; e < e1; e += 256) {
            atomicAdd(&hist[(U + sr[e]) >> CSHIFT], 1);
        }
    }
    __syncthreads();
    for (int t = threadIdx.x; t < MAXC; t += 256) {
        int h = hist[t];
        if (h) atomicAdd(&ctot[t * CPAD], h);
    }
}

// ---------------------------------------------------------------------------
// class_scan: 1-block exclusive scan over NC class totals -> bkptr;
// also re-initializes ctot[c*CPAD] as the bin-pass bucket cursor.
// ---------------------------------------------------------------------------
__global__ void __launch_bounds__(512) class_scan(int* __restrict__ ctot, int NC,
                                                  int* __restrict__ bkptr) {
    __shared__ int sh[512];
    int t = threadIdx.x;
    int v = (t < NC) ? ctot[t * CPAD] : 0;
    sh[t] = v;
    __syncthreads();
    for (int ofs = 1; ofs < 512; ofs <<= 1) {
        int x = (t >= ofs) ? sh[t - ofs] : 0;
        __syncthreads();
        sh[t] += x;
        __syncthreads();
    }
    int excl = sh[t] - v;
    if (t < NC) {
        bkptr[t] = excl;
        ctot[t * CPAD] = excl;   // becomes bucket append cursor
    }
    if (t == 511) bkptr[NC] = sh[511];
}

// ---------------------------------------------------------------------------
// bin: append entries into per-class buckets (weight-free). EPB edges/block,
// two-phase: (A) LDS-histogram count -> one padded global atomicAdd per
// (block, class) reserves a CONTIGUOUS ~28-entry chunk; (B) re-read the
// edge range (L2-hot) and append. Big chunks -> ~1.3x write amplification.
// Entry .x = (sflag<<27) | (row_lo<<18) | col ; .y = sv bits (s) or 0 (bip).
// ---------------------------------------------------------------------------
__global__ void __launch_bounds__(256) bin_kernel(const int* __restrict__ eu,
                                                  const int* __restrict__ ei,
                                                  int E, int nbE,
                                                  const int* __restrict__ sr,
                                                  const int* __restrict__ sc,
                                                  const float* __restrict__ sv, int S,
                                                  int U,
                                                  int* __restrict__ bkcur,
                                                  int2* __restrict__ bent) {
    __shared__ int hist[MAXC];
    __shared__ int base[MAXC];
    for (int t = threadIdx.x; t < MAXC; t += 256) hist[t] = 0;
    __syncthreads();

    int blk = blockIdx.x;
    if (blk < nbE) {
        int e0 = blk * EPB, e1 = min(e0 + EPB, E);
        for (int e = e0 + threadIdx.x; e < e1; e += 256) {
            atomicAdd(&hist[eu[e] >> CSHIFT], 1);
            atomicAdd(&hist[(U + ei[e]) >> CSHIFT], 1);
        }
        __syncthreads();
        for (int t = threadIdx.x; t < MAXC; t += 256) {
            int h = hist[t];
            base[t] = h ? atomicAdd(&bkcur[t * CPAD], h) : 0;
            hist[t] = 0;
        }
        __syncthreads();
        for (int e = e0 + threadIdx.x; e < e1; e += 256) {
            int u  = eu[e];
            int iv = U + ei[e];
            int c0 = u >> CSHIFT, c1 = iv >> CSHIFT;
            int o0 = atomicAdd(&hist[c0], 1);
            bent[base[c0] + o0] = make_int2(((u & CMASK) << 18) | iv, 0);
            int o1 = atomicAdd(&hist[c1], 1);
            bent[base[c1] + o1] = make_int2(((iv & CMASK) << 18) | u, 0);
        }
    } else {
        int e0 = (blk - nbE) * EPB, e1 = min(e0 + EPB, S);
        for (int e = e0 + threadIdx.x; e < e1; e += 256) {
            atomicAdd(&hist[(U + sr[e]) >> CSHIFT], 1);
        }
        __syncthreads();
        for (int t = threadIdx.x; t < MAXC; t += 256) {
            int h = hist[t];
            base[t] = h ? atomicAdd(&bkcur[t * CPAD], h) : 0;
            hist[t] = 0;
        }
        __syncthreads();
        for (int e = e0 + threadIdx.x; e < e1; e += 256) {
            int dst = U + sr[e];
            int c = dst >> CSHIFT;
            int o = atomicAdd(&hist[c], 1);
            bent[base[c] + o] = make_int2(SFLAG | ((dst & CMASK) << 18) | (U + sc[e]),
                                          __float_as_int(sv[e]));
        }
    }
}

// ---------------------------------------------------------------------------
// scatter_cls: one 1024-thread block per 512-row class. From its bucket:
// (1) LDS histograms: bip-degree + total per row -> norm = rsqrt(bipdeg+1),
// (2) LDS scan -> rowptr + cursors (no global row atomics anywhere),
// (3) re-stream bucket (L2-hot) -> exact CSR into the exclusively-owned
//     window (single XCD, temporally dense -> ~1x write amplification).
// Bip entries store (col, row|0x80000000) for the later weight fill.
// ---------------------------------------------------------------------------
__global__ void __launch_bounds__(1024) scatter_cls(const int* __restrict__ bkptr,
                                                    const int2* __restrict__ bent,
                                                    float* __restrict__ norm,
                                                    int* __restrict__ rowptr,
                                                    int2* __restrict__ ent, int M) {
    __shared__ int cntb[CROWS];
    __shared__ int cntt[CROWS];
    __shared__ int cur[CROWS];
    int c   = blockIdx.x;
    int rlo = c << CSHIFT;
    int nrows = min(CROWS, M - rlo);
    if (threadIdx.x < CROWS) {
        cntb[threadIdx.x] = 0;
        cntt[threadIdx.x] = 0;
    }
    __syncthreads();

    int beg = bkptr[c], end = bkptr[c + 1];
    for (int k = beg + threadIdx.x; k < end; k += 1024) {
        int x = bent[k].x;
        int rl = (x >> 18) & CMASK;
        atomicAdd(&cntt[rl], 1);
        if (!(x & SFLAG)) atomicAdd(&cntb[rl], 1);
    }
    __syncthreads();

    int my = 0;
    if (threadIdx.x < CROWS) {
        my = cntt[threadIdx.x];
        if (threadIdx.x < nrows)
            norm[rlo + threadIdx.x] = rsqrtf((float)cntb[threadIdx.x] + 1.0f);
    }
    for (int ofs = 1; ofs < CROWS; ofs <<= 1) {
        int x = (threadIdx.x >= ofs && threadIdx.x < CROWS) ? cntt[threadIdx.x - ofs] : 0;
        __syncthreads();
        if (threadIdx.x < CROWS) cntt[threadIdx.x] += x;
        __syncthreads();
    }
    if (threadIdx.x < CROWS) {
        int v = beg + cntt[threadIdx.x] - my;   // exclusive
        if (threadIdx.x < nrows) rowptr[rlo + threadIdx.x] = v;
        cur[threadIdx.x] = v;
    }
    if (threadIdx.x == 0) rowptr[rlo + nrows] = end;  // covers rowptr[M]
    __syncthreads();

    for (int k = beg + threadIdx.x; k < end; k += 1024) {
        int2 e = bent[k];
        int rl  = (e.x >> 18) & CMASK;
        int col = e.x & 0x3FFFF;
        int p = atomicAdd(&cur[rl], 1);
        ent[p] = (e.x & SFLAG) ? make_int2(col, e.y)
                               : make_int2(col, (rlo + rl) | (int)0x80000000);
    }
}

// ---------------------------------------------------------------------------
// fill_w: sequential pass over ent; bip entries (.y sign bit set) get
// w = norm[row]*norm[col] (bit-identical product to the original formula).
// ---------------------------------------------------------------------------
__global__ void __launch_bounds__(256) fill_w(const float* __restrict__ norm,
                                              int2* __restrict__ ent, int NT) {
    int k = blockIdx.x * 256 + threadIdx.x;
    if (k >= NT) return;
    int2 e = ent[k];
    if (e.y < 0) {
        int row = e.y & 0x7FFFFFFF;
        e.y = __float_as_int(norm[row] * norm[e.x]);
        ent[k] = e;
    }
}

// ---------------------------------------------------------------------------
// cur0 (fp16) = concat(user_emb, item_emb)
// ---------------------------------------------------------------------------
__global__ void init_kernel(const float4v* __restrict__ ue, const float4v* __restrict__ ie,
                            long u4, long total4, half4v* __restrict__ curH) {
    long stride = (long)gridDim.x * blockDim.x;
    for (long idx = (long)blockIdx.x * blockDim.x + threadIdx.x; idx < total4; idx += stride) {
        float4v v = (idx < u4) ? ue[idx] : ie[idx - u4];
        curH[idx] = __builtin_convertvector(v, half4v);
    }
}

// ---------------------------------------------------------------------------
// gather: ONE 16-lane quarter-wave per destination row (4 rows per wave),
// 4-deep masked software pipeline -> 16 outstanding row loads per wave.
// All layers read fp16 rows (128 B). fp32 accumulate.
// MODE 0: curH=e0 -> dstH=e1
// MODE 1: curH=e1 -> dstH=e2 (fp16), out = e0 + e1 + acc (acc = fp32 e2)
// MODE 2: curH=e2 -> out = 0.25*(out + acc)
// ---------------------------------------------------------------------------
template <int MODE>
__global__ void __launch_bounds__(256) gather_kernel(const int* __restrict__ rowptr,
                                                     const int2* __restrict__ ent,
                                                     const _Float16* __restrict__ curH,
                                                     const _Float16* __restrict__ cur0H,
                                                     _Float16* __restrict__ dstH,
                                                     float* __restrict__ out,
                                                     int U, int I, int M) {
    int raw = (int)((((long)blockIdx.x * blockDim.x) + threadIdx.x) >> 4);
    int l   = threadIdx.x & 15;
    if (raw >= M) return;
    int row = (raw < I) ? (U + raw) : (raw - I);   // heavy-first: items first
    int beg = rowptr[row];
    int end = rowptr[row + 1];
    const half4v* curv = (const half4v*)(const void*)curH;

    float4v acc = {0.f, 0.f, 0.f, 0.f};
    int j = beg;
    int2 a0 = (j + 0 < end) ? ent[j + 0] : make_int2(0, 0);
    int2 a1 = (j + 1 < end) ? ent[j + 1] : make_int2(0, 0);
    int2 a2 = (j + 2 < end) ? ent[j + 2] : make_int2(0, 0);
    int2 a3 = (j + 3 < end) ? ent[j + 3] : make_int2(0, 0);
    half4v v0 = curv[(long)a0.x * 16 + l];
    half4v v1 = curv[(long)a1.x * 16 + l];
    half4v v2 = curv[(long)a2.x * 16 + l];
    half4v v3 = curv[(long)a3.x * 16 + l];
    while (j + 4 < end) {
        int jn = j + 4;
        int2 b0 = (jn + 0 < end) ? ent[jn + 0] : make_int2(0, 0);
        int2 b1 = (jn + 1 < end) ? ent[jn + 1] : make_int2(0, 0);
        int2 b2 = (jn + 2 < end) ? ent[jn + 2] : make_int2(0, 0);
        int2 b3 = (jn + 3 < end) ? ent[jn + 3] : make_int2(0, 0);
        half4v u0 = curv[(long)b0.x * 16 + l];
        half4v u1 = curv[(long)b1.x * 16 + l];
        half4v u2 = curv[(long)b2.x * 16 + l];
        half4v u3 = curv[(long)b3.x * 16 + l];
        acc += __int_as_float(a0.y) * tof32(v0);
        acc += __int_as_float(a1.y) * tof32(v1);
        acc += __int_as_float(a2.y) * tof32(v2);
        acc += __int_as_float(a3.y) * tof32(v3);
        a0 = b0; a1 = b1; a2 = b2; a3 = b3;
        v0 = u0; v1 = u1; v2 = u2; v3 = u3;
        j = jn;
    }
    acc += __int_as_float(a0.y) * tof32(v0);
    acc += __int_as_float(a1.y) * tof32(v1);
    acc += __int_as_float(a2.y) * tof32(v2);
    acc += __int_as_float(a3.y) * tof32(v3);

    long o4 = (long)row * 16 + l;
    if (MODE == 0) {
        ((half4v*)dstH)[o4] = __builtin_convertvector(acc, half4v);
    } else if (MODE == 1) {
        float4v e0 = tof32(((const half4v*)cur0H)[o4]);
        float4v e1 = tof32(curv[o4]);
        ((half4v*)dstH)[o4] = __builtin_convertvector(acc, half4v);  // e2 (fp16)
        ((float4v*)out)[o4] = e0 + e1 + acc;      // partial sum (fp32 e2)
    } else {
        float4v pv = ((const float4v*)out)[o4];
        ((float4v*)out)[o4] = 0.25f * (pv + acc);
    }
}

extern "C" void kernel_launch(void* const* d_in, const int* in_sizes, int n_in,
                              void* d_out, int out_size, void* d_ws, size_t ws_size,
                              hipStream_t stream) {
    const float* user_emb = (const float*)d_in[0];
    const float* item_emb = (const float*)d_in[1];
    const int*   edge_user = (const int*)d_in[2];
    const int*   edge_item = (const int*)d_in[3];
    const int*   s_row = (const int*)d_in[4];
    const int*   s_col = (const int*)d_in[5];
    const float* s_val = (const float*)d_in[6];
    float* out = (float*)d_out;

    const int U = in_sizes[0] / EMB_D;
    const int I = in_sizes[1] / EMB_D;
    const int M = U + I;
    const int E = in_sizes[2];
    const int S = in_sizes[4];
    const long MD = (long)M * EMB_D;
    const long NT = 2L * E + S;             // merged CSR entries
    const int NC = (M + CMASK) >> CSHIFT;   // number of row classes

    // workspace carve-up, 16B-aligned chunks
    char* p = (char*)d_ws;
    auto carve = [&](long bytes) {
        char* q = p;
        p += (bytes + 15) & ~15L;
        return q;
    };
    _Float16* cur0H = (_Float16*)carve(MD * sizeof(_Float16));  // e0 (fp16)
    _Float16* cur1H = (_Float16*)carve(MD * sizeof(_Float16));  // e1 (fp16)
    // cur2H (e2, fp16) aliases the bucket array: bucket dead before e2 written
    long aliasBytes = MD * (long)sizeof(_Float16) > (NT + 8) * (long)sizeof(int2)
                        ? MD * (long)sizeof(_Float16) : (NT + 8) * (long)sizeof(int2);
    char* aliasRgn = carve(aliasBytes);
    _Float16* cur2H = (_Float16*)aliasRgn;
    int2*     bent  = (int2*)aliasRgn;
    float* norm   = (float*)carve((long)M * sizeof(float));
    int*   rowptr = (int*)carve((long)(M + 1) * sizeof(int));
    int*   ctot   = (int*)carve((long)MAXC * CPAD * sizeof(int)); // counters/cursors
    int*   bkptr  = (int*)carve((long)(MAXC + 1) * sizeof(int));
    int2*  ent    = (int2*)carve((NT + 8) * sizeof(int2));

    const int nbE2 = (E + EPB - 1) / EPB;
    const int nbS2 = (S + EPB - 1) / EPB;

    // 1) per-class counts (LDS-aggregated, padded class counters)
    hipMemsetAsync(ctot, 0, (size_t)MAXC * CPAD * sizeof(int), stream);
    class_cnt<<<nbE2 + nbS2, 256, 0, stream>>>(edge_user, edge_item, E, nbE2,
                                               s_row, S, U, ctot);

    // 2) class scan -> bkptr; ctot becomes the bin append cursor
    class_scan<<<1, 512, 0, stream>>>(ctot, NC, bkptr);

    // 3) bin entries into class buckets (two-phase, big contiguous chunks)
    bin_kernel<<<nbE2 + nbS2, 256, 0, stream>>>(edge_user, edge_item, E, nbE2,
                                                s_row, s_col, s_val, S,
                                                U, ctot, bent);

    // 4) per-class: degrees->norm, scan->rowptr, scatter->CSR (all in LDS)
    scatter_cls<<<NC, 1024, 0, stream>>>(bkptr, bent, norm, rowptr, ent, M);

    // 5) weight fill for bip entries
    fill_w<<<(int)((NT + 255) / 256), 256, 0, stream>>>(norm, ent, (int)NT);

    // 6) init cur0 (fp16)
    init_kernel<<<2048, 256, 0, stream>>>((const float4v*)user_emb, (const float4v*)item_emb,
                                          (long)U * (EMB_D / 4), MD / 4, (half4v*)cur0H);

    // 7) L=3 gather layers, all fp16 row reads
    const int gblocks = (int)(((long)M * 16 + 255) / 256);
    gather_kernel<0><<<gblocks, 256, 0, stream>>>(rowptr, ent, cur0H, nullptr,
                                                  cur1H, nullptr, U, I, M);
    gather_kernel<1><<<gblocks, 256, 0, stream>>>(rowptr, ent, cur1H, cur0H,
                                                  cur2H, out, U, I, M);
    gather_kernel<2><<<gblocks, 256, 0, stream>>>(rowptr, ent, cur2H, nullptr,
                                                  nullptr, out, U, I, M);
}

// Round 16
// 240.761 us; speedup vs baseline: 12.9648x; 1.1408x over previous
//
#include <hip/hip_runtime.h>

#define EMB_D 64
#define CSHIFT 9    // class = row >> 9 (512 rows/class)
#define CROWS  (1 << CSHIFT)
#define CMASK  (CROWS - 1)
#define MAXC 384    // max classes (M <= 196608; col fits 18 bits)
#define SFLAG (1 << 27)
#define EPB 4096    // edges per bin/count block (16 per thread)

typedef float    float4v __attribute__((ext_vector_type(4)));
typedef float    float8v __attribute__((ext_vector_type(8)));
typedef _Float16 half4v  __attribute__((ext_vector_type(4)));
typedef _Float16 half8v  __attribute__((ext_vector_type(8)));

__device__ inline float8v tof32x8(half8v v) { return __builtin_convertvector(v, float8v); }

// ---------------------------------------------------------------------------
// class_cnt: per-block per-class entry counts. EPB edges/block, LDS
// histogram -> DENSE row store percls[blk][c] (no global atomics at all).
// ---------------------------------------------------------------------------
__global__ void __launch_bounds__(256) class_cnt(const int* __restrict__ eu,
                                                 const int* __restrict__ ei,
                                                 int E, int nbE,
                                                 const int* __restrict__ sr, int S,
                                                 int U, int* __restrict__ percls) {
    __shared__ int hist[MAXC];
    for (int t = threadIdx.x; t < MAXC; t += 256) hist[t] = 0;
    __syncthreads();
    int blk = blockIdx.x;
    if (blk < nbE) {
        int e0 = blk * EPB, e1 = min(e0 + EPB, E);
        for (int e = e0 + threadIdx.x; e < e1; e += 256) {
            atomicAdd(&hist[eu[e] >> CSHIFT], 1);
            atomicAdd(&hist[(U + ei[e]) >> CSHIFT], 1);
        }
    } else {
        int e0 = (blk - nbE) * EPB, e1 = min(e0 + EPB, S);
        for (int e = e0 + threadIdx.x; e < e1; e += 256) {
            atomicAdd(&hist[(U + sr[e]) >> CSHIFT], 1);
        }
    }
    __syncthreads();
    for (int t = threadIdx.x; t < MAXC; t += 256)
        percls[(long)blk * MAXC + t] = hist[t];
}

// ---------------------------------------------------------------------------
// colscan: one block per class c. Exclusive scan over blocks of
// percls[blk][c] -> per-block chunk base offsets; total -> ctot[c].
// ---------------------------------------------------------------------------
__global__ void __launch_bounds__(512) colscan(int* __restrict__ percls, int NB,
                                               int* __restrict__ ctot) {
    __shared__ int sh[512];
    int c = blockIdx.x;
    int t = threadIdx.x;
    int v = (t < NB) ? percls[(long)t * MAXC + c] : 0;
    sh[t] = v;
    __syncthreads();
    for (int ofs = 1; ofs < 512; ofs <<= 1) {
        int x = (t >= ofs) ? sh[t - ofs] : 0;
        __syncthreads();
        sh[t] += x;
        __syncthreads();
    }
    if (t < NB) percls[(long)t * MAXC + c] = sh[t] - v;  // exclusive
    if (t == 511) ctot[c] = sh[511];
}

// ---------------------------------------------------------------------------
// class_scan: 1-block exclusive scan over NC class totals -> bkptr.
// ---------------------------------------------------------------------------
__global__ void __launch_bounds__(512) class_scan(const int* __restrict__ ctot, int NC,
                                                  int* __restrict__ bkptr) {
    __shared__ int sh[512];
    int t = threadIdx.x;
    int v = (t < NC) ? ctot[t] : 0;
    sh[t] = v;
    __syncthreads();
    for (int ofs = 1; ofs < 512; ofs <<= 1) {
        int x = (t >= ofs) ? sh[t - ofs] : 0;
        __syncthreads();
        sh[t] += x;
        __syncthreads();
    }
    if (t < NC) bkptr[t] = sh[t] - v;
    if (t == 511) bkptr[NC] = sh[511];
}

// ---------------------------------------------------------------------------
// bin: single-pass append into per-class buckets. Chunk base comes from
// bkptr[c] + percls[blk][c] (precomputed, no global atomics); intra-chunk
// offset via LDS hist. ~28-entry contiguous chunks -> ~1.3x write amp.
// Entry .x = (sflag<<27) | (row_lo<<18) | col ; .y = sv bits (s) or 0 (bip).
// ---------------------------------------------------------------------------
__global__ void __launch_bounds__(256) bin_kernel(const int* __restrict__ eu,
                                                  const int* __restrict__ ei,
                                                  int E, int nbE,
                                                  const int* __restrict__ sr,
                                                  const int* __restrict__ sc,
                                                  const float* __restrict__ sv, int S,
                                                  int U,
                                                  const int* __restrict__ bkptr,
                                                  const int* __restrict__ percls,
                                                  int2* __restrict__ bent) {
    __shared__ int hist[MAXC];
    __shared__ int base[MAXC];
    int blk = blockIdx.x;
    for (int t = threadIdx.x; t < MAXC; t += 256) {
        base[t] = bkptr[t] + percls[(long)blk * MAXC + t];
        hist[t] = 0;
    }
    __syncthreads();

    if (blk < nbE) {
        int e0 = blk * EPB, e1 = min(e0 + EPB, E);
        for (int e = e0 + threadIdx.x; e < e1; e += 256) {
            int u  = eu[e];
            int iv = U + ei[e];
            int c0 = u >> CSHIFT, c1 = iv >> CSHIFT;
            int o0 = atomicAdd(&hist[c0], 1);
            bent[base[c0] + o0] = make_int2(((u & CMASK) << 18) | iv, 0);
            int o1 = atomicAdd(&hist[c1], 1);
            bent[base[c1] + o1] = make_int2(((iv & CMASK) << 18) | u, 0);
        }
    } else {
        int e0 = (blk - nbE) * EPB, e1 = min(e0 + EPB, S);
        for (int e = e0 + threadIdx.x; e < e1; e += 256) {
            int dst = U + sr[e];
            int c = dst >> CSHIFT;
            int o = atomicAdd(&hist[c], 1);
            bent[base[c] + o] = make_int2(SFLAG | ((dst & CMASK) << 18) | (U + sc[e]),
                                          __float_as_int(sv[e]));
        }
    }
}

// ---------------------------------------------------------------------------
// scatter_cls: one 1024-thread block per 512-row class. From its bucket:
// (1) LDS histograms: bip-degree + total per row -> norm = rsqrt(bipdeg+1),
// (2) LDS scan -> rowptr + cursors (no global row atomics anywhere),
// (3) re-stream bucket (L2-hot) -> exact CSR into the exclusively-owned
//     window (single XCD, temporally dense -> ~1x write amplification).
// Bip entries store (col, row|0x80000000) for the later weight fill.
// ---------------------------------------------------------------------------
__global__ void __launch_bounds__(1024) scatter_cls(const int* __restrict__ bkptr,
                                                    const int2* __restrict__ bent,
                                                    float* __restrict__ norm,
                                                    int* __restrict__ rowptr,
                                                    int2* __restrict__ ent, int M) {
    __shared__ int cntb[CROWS];
    __shared__ int cntt[CROWS];
    __shared__ int cur[CROWS];
    int c   = blockIdx.x;
    int rlo = c << CSHIFT;
    int nrows = min(CROWS, M - rlo);
    if (threadIdx.x < CROWS) {
        cntb[threadIdx.x] = 0;
        cntt[threadIdx.x] = 0;
    }
    __syncthreads();

    int beg = bkptr[c], end = bkptr[c + 1];
    for (int k = beg + threadIdx.x; k < end; k += 1024) {
        int x = bent[k].x;
        int rl = (x >> 18) & CMASK;
        atomicAdd(&cntt[rl], 1);
        if (!(x & SFLAG)) atomicAdd(&cntb[rl], 1);
    }
    __syncthreads();

    int my = 0;
    if (threadIdx.x < CROWS) {
        my = cntt[threadIdx.x];
        if (threadIdx.x < nrows)
            norm[rlo + threadIdx.x] = rsqrtf((float)cntb[threadIdx.x] + 1.0f);
    }
    for (int ofs = 1; ofs < CROWS; ofs <<= 1) {
        int x = (threadIdx.x >= ofs && threadIdx.x < CROWS) ? cntt[threadIdx.x - ofs] : 0;
        __syncthreads();
        if (threadIdx.x < CROWS) cntt[threadIdx.x] += x;
        __syncthreads();
    }
    if (threadIdx.x < CROWS) {
        int v = beg + cntt[threadIdx.x] - my;   // exclusive
        if (threadIdx.x < nrows) rowptr[rlo + threadIdx.x] = v;
        cur[threadIdx.x] = v;
    }
    if (threadIdx.x == 0) rowptr[rlo + nrows] = end;  // covers rowptr[M]
    __syncthreads();

    for (int k = beg + threadIdx.x; k < end; k += 1024) {
        int2 e = bent[k];
        int rl  = (e.x >> 18) & CMASK;
        int col = e.x & 0x3FFFF;
        int p = atomicAdd(&cur[rl], 1);
        ent[p] = (e.x & SFLAG) ? make_int2(col, e.y)
                               : make_int2(col, (rlo + rl) | (int)0x80000000);
    }
}

// ---------------------------------------------------------------------------
// fill_w: sequential pass over ent; bip entries (.y sign bit set) get
// w = norm[row]*norm[col] (bit-identical product to the original formula).
// ---------------------------------------------------------------------------
__global__ void __launch_bounds__(256) fill_w(const float* __restrict__ norm,
                                              int2* __restrict__ ent, int NT) {
    int k = blockIdx.x * 256 + threadIdx.x;
    if (k >= NT) return;
    int2 e = ent[k];
    if (e.y < 0) {
        int row = e.y & 0x7FFFFFFF;
        e.y = __float_as_int(norm[row] * norm[e.x]);
        ent[k] = e;
    }
}

// ---------------------------------------------------------------------------
// cur0 (fp16) = concat(user_emb, item_emb)
// ---------------------------------------------------------------------------
__global__ void init_kernel(const float4v* __restrict__ ue, const float4v* __restrict__ ie,
                            long u4, long total4, half4v* __restrict__ curH) {
    long stride = (long)gridDim.x * blockDim.x;
    for (long idx = (long)blockIdx.x * blockDim.x + threadIdx.x; idx < total4; idx += stride) {
        float4v v = (idx < u4) ? ue[idx] : ie[idx - u4];
        curH[idx] = __builtin_convertvector(v, half4v);
    }
}

// ---------------------------------------------------------------------------
// gather: ONE 8-lane group per destination row (8 rows per wave), half8
// 16 B loads (full 128 B row per group), 4-deep masked software pipeline ->
// 32 outstanding row loads per wave. Heavy-first: item rows first.
// MODE 0: curH=e0 -> dstH=e1
// MODE 1: curH=e1 -> dstH=e2 (fp16), out = e0 + e1 + acc (fp32 e2)
// MODE 2: curH=e2 -> out = 0.25*(out + acc)
// ---------------------------------------------------------------------------
template <int MODE>
__global__ void __launch_bounds__(256) gather_kernel(const int* __restrict__ rowptr,
                                                     const int2* __restrict__ ent,
                                                     const _Float16* __restrict__ curH,
                                                     const _Float16* __restrict__ cur0H,
                                                     _Float16* __restrict__ dstH,
                                                     float* __restrict__ out,
                                                     int U, int I, int M) {
    int raw = (int)((((long)blockIdx.x * blockDim.x) + threadIdx.x) >> 3);
    int l   = threadIdx.x & 7;
    if (raw >= M) return;
    int row = (raw < I) ? (U + raw) : (raw - I);   // heavy-first: items first
    int beg = rowptr[row];
    int end = rowptr[row + 1];
    const half8v* curv = (const half8v*)(const void*)curH;

    float8v acc = {0.f, 0.f, 0.f, 0.f, 0.f, 0.f, 0.f, 0.f};
    int j = beg;
    int2 a0 = (j + 0 < end) ? ent[j + 0] : make_int2(0, 0);
    int2 a1 = (j + 1 < end) ? ent[j + 1] : make_int2(0, 0);
    int2 a2 = (j + 2 < end) ? ent[j + 2] : make_int2(0, 0);
    int2 a3 = (j + 3 < end) ? ent[j + 3] : make_int2(0, 0);
    half8v v0 = curv[(long)a0.x * 8 + l];
    half8v v1 = curv[(long)a1.x * 8 + l];
    half8v v2 = curv[(long)a2.x * 8 + l];
    half8v v3 = curv[(long)a3.x * 8 + l];
    while (j + 4 < end) {
        int jn = j + 4;
        int2 b0 = (jn + 0 < end) ? ent[jn + 0] : make_int2(0, 0);
        int2 b1 = (jn + 1 < end) ? ent[jn + 1] : make_int2(0, 0);
        int2 b2 = (jn + 2 < end) ? ent[jn + 2] : make_int2(0, 0);
        int2 b3 = (jn + 3 < end) ? ent[jn + 3] : make_int2(0, 0);
        half8v u0 = curv[(long)b0.x * 8 + l];
        half8v u1 = curv[(long)b1.x * 8 + l];
        half8v u2 = curv[(long)b2.x * 8 + l];
        half8v u3 = curv[(long)b3.x * 8 + l];
        acc += __int_as_float(a0.y) * tof32x8(v0);
        acc += __int_as_float(a1.y) * tof32x8(v1);
        acc += __int_as_float(a2.y) * tof32x8(v2);
        acc += __int_as_float(a3.y) * tof32x8(v3);
        a0 = b0; a1 = b1; a2 = b2; a3 = b3;
        v0 = u0; v1 = u1; v2 = u2; v3 = u3;
        j = jn;
    }
    acc += __int_as_float(a0.y) * tof32x8(v0);
    acc += __int_as_float(a1.y) * tof32x8(v1);
    acc += __int_as_float(a2.y) * tof32x8(v2);
    acc += __int_as_float(a3.y) * tof32x8(v3);

    long o8 = (long)row * 8 + l;
    if (MODE == 0) {
        ((half8v*)dstH)[o8] = __builtin_convertvector(acc, half8v);
    } else if (MODE == 1) {
        float8v e0 = tof32x8(((const half8v*)cur0H)[o8]);
        float8v e1 = tof32x8(curv[o8]);
        ((half8v*)dstH)[o8] = __builtin_convertvector(acc, half8v);  // e2 (fp16)
        ((float8v*)out)[o8] = e0 + e1 + acc;      // partial sum (fp32 e2)
    } else {
        float8v pv = ((const float8v*)out)[o8];
        ((float8v*)out)[o8] = 0.25f * (pv + acc);
    }
}

extern "C" void kernel_launch(void* const* d_in, const int* in_sizes, int n_in,
                              void* d_out, int out_size, void* d_ws, size_t ws_size,
                              hipStream_t stream) {
    const float* user_emb = (const float*)d_in[0];
    const float* item_emb = (const float*)d_in[1];
    const int*   edge_user = (const int*)d_in[2];
    const int*   edge_item = (const int*)d_in[3];
    const int*   s_row = (const int*)d_in[4];
    const int*   s_col = (const int*)d_in[5];
    const float* s_val = (const float*)d_in[6];
    float* out = (float*)d_out;

    const int U = in_sizes[0] / EMB_D;
    const int I = in_sizes[1] / EMB_D;
    const int M = U + I;
    const int E = in_sizes[2];
    const int S = in_sizes[4];
    const long MD = (long)M * EMB_D;
    const long NT = 2L * E + S;             // merged CSR entries
    const int NC = (M + CMASK) >> CSHIFT;   // number of row classes

    const int nbE2 = (E + EPB - 1) / EPB;
    const int nbS2 = (S + EPB - 1) / EPB;
    const int NB = nbE2 + nbS2;             // <= 512 for these sizes

    // workspace carve-up, 16B-aligned chunks
    char* p = (char*)d_ws;
    auto carve = [&](long bytes) {
        char* q = p;
        p += (bytes + 15) & ~15L;
        return q;
    };
    _Float16* cur0H = (_Float16*)carve(MD * sizeof(_Float16));  // e0 (fp16)
    _Float16* cur1H = (_Float16*)carve(MD * sizeof(_Float16));  // e1 (fp16)
    // cur2H (e2, fp16) aliases the bucket array: bucket dead before e2 written
    long aliasBytes = MD * (long)sizeof(_Float16) > (NT + 8) * (long)sizeof(int2)
                        ? MD * (long)sizeof(_Float16) : (NT + 8) * (long)sizeof(int2);
    char* aliasRgn = carve(aliasBytes);
    _Float16* cur2H = (_Float16*)aliasRgn;
    int2*     bent  = (int2*)aliasRgn;
    float* norm   = (float*)carve((long)M * sizeof(float));
    int*   rowptr = (int*)carve((long)(M + 1) * sizeof(int));
    int*   percls = (int*)carve((long)NB * MAXC * sizeof(int));
    int*   ctot   = (int*)carve((long)MAXC * sizeof(int));
    int*   bkptr  = (int*)carve((long)(MAXC + 1) * sizeof(int));
    int2*  ent    = (int2*)carve((NT + 8) * sizeof(int2));

    // 1) per-block per-class counts (dense stores, zero global atomics)
    class_cnt<<<NB, 256, 0, stream>>>(edge_user, edge_item, E, nbE2,
                                      s_row, S, U, percls);

    // 2) column scan over blocks -> chunk bases; class scan -> bkptr
    colscan<<<NC, 512, 0, stream>>>(percls, NB, ctot);
    class_scan<<<1, 512, 0, stream>>>(ctot, NC, bkptr);

    // 3) single-pass bin into class buckets (precomputed chunk bases)
    bin_kernel<<<NB, 256, 0, stream>>>(edge_user, edge_item, E, nbE2,
                                       s_row, s_col, s_val, S,
                                       U, bkptr, percls, bent);

    // 4) per-class: degrees->norm, scan->rowptr, scatter->CSR (all in LDS)
    scatter_cls<<<NC, 1024, 0, stream>>>(bkptr, bent, norm, rowptr, ent, M);

    // 5) weight fill for bip entries
    fill_w<<<(int)((NT + 255) / 256), 256, 0, stream>>>(norm, ent, (int)NT);

    // 6) init cur0 (fp16)
    init_kernel<<<2048, 256, 0, stream>>>((const float4v*)user_emb, (const float4v*)item_emb,
                                          (long)U * (EMB_D / 4), MD / 4, (half4v*)cur0H);

    // 7) L=3 gather layers, 8-lane groups x half8
    const int gblocks = (int)(((long)M * 8 + 255) / 256);
    gather_kernel<0><<<gblocks, 256, 0, stream>>>(rowptr, ent, cur0H, nullptr,
                                                  cur1H, nullptr, U, I, M);
    gather_kernel<1><<<gblocks, 256, 0, stream>>>(rowptr, ent, cur1H, cur0H,
                                                  cur2H, out, U, I, M);
    gather_kernel<2><<<gblocks, 256, 0, stream>>>(rowptr, ent, cur2H, nullptr,
                                                  nullptr, out, U, I, M);
}